// Round 5
// baseline (882.955 us; speedup 1.0000x reference)
//
#include <hip/hip_runtime.h>
#include <math.h>

// ---------------------------------------------------------------------------
// Sizes
// ---------------------------------------------------------------------------
#define Bn 256
#define Sn 3
#define Ln 4096
#define Gn 768          // B*S
#define TDn 256
#define TLn 2

// Workspace layout (float offsets)
#define WS_W1K   0        // 1024 fl  (2048 f16)   [br][oc32][k32]
#define WS_W2K   1024     // 14336 fl (28672 f16)  [br][oc64][k224]
#define WS_W3K   15360    // 24576 fl (49152 f16)  [br][oc128][k192]
#define WS_H1    39936    // 64
#define WS_H2    40000    // 128
#define WS_H3    40128    // 256
#define WS_FPWH  40960    // 131072 fl = 262144 f16  fpw [256][1024]
#define WS_INWH  172032   // 196608 fl = 393216 f16  [TL][768][256]
#define WS_OUTWH 368640   // 65536 fl  = 131072 f16  [TL][256][256]
#define WS_L1WH  434176   // 262144 fl = 524288 f16  [TL][1024][256]
#define WS_L2WH  696320   // 262144 fl = 524288 f16  [TL][256][1024]
#define WS_POOL  958464   // 196608 fl f32 [768][256]  (dead after gat ->)
#define WS_XH    958464   //   98304 fl = 196608 f16 [768][256]
#define WS_ABH   1056768  //   98304 fl = 196608 f16 [768][256]
#define WS_SCR   1155072  // 589824 fl: GOUTH f16[768][1024] | QKV f32[768][768] | MIDH f16[768][1024]
#define WS_Y     1548288  // 196608 fl (unused this round)
#define WS_X     1744896  // 196608 fl f32 [768][256]
// end: 1941504 floats = 7.77 MB

typedef _Float16 f16x8 __attribute__((ext_vector_type(8)));
typedef float f32x4 __attribute__((ext_vector_type(4)));
#define MFMA16(a,b,c) __builtin_amdgcn_mfma_f32_16x16x32_f16(a,b,c,0,0,0)

// ---------------------------------------------------------------------------
// K0a: conv weight transpose to f16 + BN fold
// ---------------------------------------------------------------------------
__global__ __launch_bounds__(256) void prep_kernel(
    const float* __restrict__ w1, const float* __restrict__ w2, const float* __restrict__ w3,
    const float* __restrict__ c1b, const float* __restrict__ g1, const float* __restrict__ b1,
    const float* __restrict__ m1, const float* __restrict__ v1,
    const float* __restrict__ c2b, const float* __restrict__ g2, const float* __restrict__ b2,
    const float* __restrict__ m2, const float* __restrict__ v2,
    const float* __restrict__ c3b, const float* __restrict__ g3, const float* __restrict__ b3,
    const float* __restrict__ m3, const float* __restrict__ v3,
    float* __restrict__ ws)
{
    int i = blockIdx.x * 256 + threadIdx.x;
    _Float16* w1k = (_Float16*)(ws + WS_W1K);
    _Float16* w2k = (_Float16*)(ws + WS_W2K);
    _Float16* w3k = (_Float16*)(ws + WS_W3K);
    if (i < 2048) { // i = (br*32+oc)*32 + c*16+tau
        int k = i & 31, oc = (i >> 5) & 31, br = i >> 10;
        int c = k >> 4, tau = k & 15;
        int a = br * 32 + oc;
        float s = g1[a] / sqrtf(v1[a] + 1e-5f);
        float v = (tau < 15) ? w1[(((size_t)a * 2 + c) * 15) + tau] * s : 0.f;
        w1k[i] = (_Float16)v;
    }
    if (i < 28672) { // i = (br*64+oc)*224 + tblk*32+ic
        int k = i % 224; int a = i / 224;
        int tblk = k >> 5, ic = k & 31;
        int t = (tblk < 4) ? 2 * tblk : 2 * (tblk - 4) + 1;
        float s = g2[a] / sqrtf(v2[a] + 1e-5f);
        w2k[i] = (_Float16)(w2[((size_t)a * 32 + ic) * 7 + t] * s);
    }
    if (i < 49152) { // i = (br*128+oc)*192 + t*64+ic
        int k = i % 192; int a = i / 192;
        int t = k >> 6, ic = k & 63;
        float s = g3[a] / sqrtf(v3[a] + 1e-5f);
        w3k[i] = (_Float16)(w3[((size_t)a * 64 + ic) * 3 + t] * s);
    }
    if (i < 64)  { float s = g1[i] / sqrtf(v1[i] + 1e-5f); ws[WS_H1 + i] = (c1b[i] - m1[i]) * s + b1[i]; }
    if (i < 128) { float s = g2[i] / sqrtf(v2[i] + 1e-5f); ws[WS_H2 + i] = (c2b[i] - m2[i]) * s + b2[i]; }
    if (i < 256) { float s = g3[i] / sqrtf(v3[i] + 1e-5f); ws[WS_H3 + i] = (c3b[i] - m3[i]) * s + b3[i]; }
}

// ---------------------------------------------------------------------------
// K0b: transformer / feat_proj weights -> f16 (layouts already [N][K])
// ---------------------------------------------------------------------------
__global__ __launch_bounds__(256) void prep_tr_kernel(
    const float* __restrict__ fpw, const float* __restrict__ inw,
    const float* __restrict__ outw, const float* __restrict__ l1w,
    const float* __restrict__ l2w, float* __restrict__ ws)
{
    int i = blockIdx.x * 256 + threadIdx.x;
    _Float16* fpwh = (_Float16*)(ws + WS_FPWH);
    _Float16* inwh = (_Float16*)(ws + WS_INWH);
    _Float16* outwh = (_Float16*)(ws + WS_OUTWH);
    _Float16* l1wh = (_Float16*)(ws + WS_L1WH);
    _Float16* l2wh = (_Float16*)(ws + WS_L2WH);
    if (i < 262144) fpwh[i] = (_Float16)fpw[i];
    if (i < 393216) inwh[i] = (_Float16)inw[i];
    if (i < 131072) outwh[i] = (_Float16)outw[i];
    if (i < 524288) { l1wh[i] = (_Float16)l1w[i]; l2wh[i] = (_Float16)l2w[i]; }
}

// ---------------------------------------------------------------------------
// K1: fused conv1->conv2->conv3->mean-pool via fp16 MFMA.
// Round-5: __launch_bounds__(256,4) caps regs ~128/wave -> 4 blocks/CU
// (round-4's (256,2) let the allocator balloon to 2 waves/SIMD = the 22%
// occupancy). conv2 split into two jj passes to fit. Pool combined through
// LDS pbuf (block exclusively owns its 128 oc) -> no global atomics/memset.
// ---------------------------------------------------------------------------
__global__ __launch_bounds__(256, 4) void conv_mfma_kernel(
    const float* __restrict__ x_t, const float* __restrict__ x_f,
    const float* __restrict__ ws, float* __restrict__ pooled)
{
    __shared__ _Float16 xsf[2 * 576];       // [c][l], f16
    __shared__ _Float16 y1[2][132 * 32];    // [parity][row i][ic granule-swizzled]
    __shared__ _Float16 y2s[128 * 64];      // [row n][oc granule-swizzled]
    __shared__ float h1s[32];
    __shared__ float h2s[64];
    __shared__ float h3s[128];
    __shared__ float pbuf[128];

    const int g = blockIdx.x, br = blockIdx.y;
    const int tid = threadIdx.x;
    const int lane = tid & 63, wv = tid >> 6;
    const int l15 = lane & 15, q4 = lane >> 4;

    const float* xin = (br == 0 ? x_t : x_f) + (size_t)g * (Ln * 2);
    const _Float16* w1k = (const _Float16*)(ws + WS_W1K) + br * 1024;
    const _Float16* w2k = (const _Float16*)(ws + WS_W2K) + br * 14336;
    const _Float16* w3k = (const _Float16*)(ws + WS_W3K) + br * 24576;

    if (tid < 32)  h1s[tid] = ws[WS_H1 + br * 32 + tid];
    if (tid < 64)  h2s[tid] = ws[WS_H2 + br * 64 + tid];
    if (tid < 128) { h3s[tid] = ws[WS_H3 + br * 128 + tid]; pbuf[tid] = 0.f; }

    // conv1 A-frags (weights, resident, 8 VGPRs): A[m=l15][k=q4*8+j]
    f16x8 a1[2];
    #pragma unroll
    for (int mt = 0; mt < 2; ++mt)
        a1[mt] = *(const f16x8*)(w1k + (mt * 16 + l15) * 32 + q4 * 8);

    const int mg = wv & 1, ng = wv >> 1;

    // per-wave weight row bases
    const _Float16* w2row = w2k + (size_t)l15 * 224 + q4 * 8;
    const _Float16* w3row = w3k + (size_t)(mg * 64 + l15) * 192 + q4 * 8;

    float pool_[4][4];
    #pragma unroll
    for (int mt = 0; mt < 4; ++mt)
        #pragma unroll
        for (int r = 0; r < 4; ++r) pool_[mt][r] = 0.f;

    const f32x4 vzero = {0.f, 0.f, 0.f, 0.f};

    #pragma unroll 1
    for (int tile = 0; tile < 9; ++tile) {
        const int P0 = tile * 126;
        const int Q0 = 2 * P0 - 5;
        const int x0 = 4 * P0 - 17;

        // ---- stage x slice -> f16 LDS ----
        for (int l = tid; l < 576; l += 256) {
            int xl = x0 + l;
            float a = 0.f, b = 0.f;
            if (xl >= 0 && xl < Ln) { float2 v = *(const float2*)(xin + (size_t)xl * 2); a = v.x; b = v.y; }
            xsf[l] = (_Float16)a; xsf[576 + l] = (_Float16)b;
        }
        __syncthreads();

        // ---- conv1 MFMA: M=32 (2 tiles), N=261 (17 tiles), K=32 ----
        const uint* xsu = (const uint*)xsf;
        #pragma unroll 1
        for (int nt = wv; nt < 17; nt += 4) {
            int j0 = nt * 16 + l15;
            union { f16x8 v; uint u[4]; } bf;
            int ubase = (q4 >> 1) * 288 + j0 + (q4 & 1) * 4;
            #pragma unroll
            for (int ii = 0; ii < 4; ++ii) bf.u[ii] = xsu[ubase + ii];
            f32x4 c1acc[2] = {vzero, vzero};
            c1acc[0] = MFMA16(a1[0], bf.v, c1acc[0]);
            c1acc[1] = MFMA16(a1[1], bf.v, c1acc[1]);

            if (j0 <= 260) {
                int q = Q0 + j0;
                bool val = (q >= 0) && (q < 2048);
                int i = j0 >> 1, par = j0 & 1;
                #pragma unroll
                for (int mt = 0; mt < 2; ++mt) {
                    int oc0 = mt * 16 + q4 * 4;
                    union { _Float16 h[4]; uint2 u; } pk;
                    #pragma unroll
                    for (int r = 0; r < 4; ++r) {
                        float y = c1acc[mt][r] + h1s[oc0 + r];
                        y = y > 0.f ? y : 0.f;
                        pk.h[r] = val ? (_Float16)y : (_Float16)0.f;
                    }
                    int gq = mt * 2 + (q4 >> 1), sub = q4 & 1;
                    *(uint2*)(&y1[par][(i * 4 + (gq ^ (i & 3))) * 8 + sub * 4]) = pk.u;
                }
            }
        }
        __syncthreads();

        // ---- conv2 MFMA: M=64 (4 tiles), N=128, K=224; two jj passes ----
        #pragma unroll 1
        for (int jj = 0; jj < 2; ++jj) {
            f32x4 c2[4] = {vzero, vzero, vzero, vzero};
            f16x8 a2c[4];
            #pragma unroll
            for (int mt = 0; mt < 4; ++mt)
                a2c[mt] = *(const f16x8*)(w2row + (size_t)mt * 16 * 224);
            const int n = wv * 32 + jj * 16 + l15;
            #pragma unroll 1
            for (int ks = 0; ks < 7; ++ks) {
                int roff = (ks < 4) ? ks : ks - 4;
                const _Float16* yb = y1[(ks < 4) ? 0 : 1];
                int i = n + roff;
                f16x8 bb = *(const f16x8*)(yb + (i * 4 + (q4 ^ (i & 3))) * 8);
                f16x8 a2n[4];
                if (ks < 6) {
                    #pragma unroll
                    for (int mt = 0; mt < 4; ++mt)
                        a2n[mt] = *(const f16x8*)(w2row + (size_t)mt * 16 * 224 + (ks + 1) * 32);
                }
                #pragma unroll
                for (int mt = 0; mt < 4; ++mt)
                    c2[mt] = MFMA16(a2c[mt], bb, c2[mt]);
                if (ks < 6) {
                    #pragma unroll
                    for (int mt = 0; mt < 4; ++mt) a2c[mt] = a2n[mt];
                }
            }
            int p2 = P0 - 1 + n;
            bool val = (p2 >= 0) && (p2 < 1024);
            #pragma unroll
            for (int mt = 0; mt < 4; ++mt) {
                int oc0 = mt * 16 + q4 * 4;
                union { _Float16 h[4]; uint2 u; } pk;
                #pragma unroll
                for (int r = 0; r < 4; ++r) {
                    float y = c2[mt][r] + h2s[oc0 + r];
                    y = y > 0.f ? y : 0.f;
                    pk.h[r] = val ? (_Float16)y : (_Float16)0.f;
                }
                int gq = oc0 >> 3, sub = q4 & 1;
                *(uint2*)(&y2s[(n * 8 + (gq ^ (n & 7))) * 8 + sub * 4]) = pk.u;
            }
        }
        __syncthreads();

        // ---- conv3 MFMA + pool: M=128, N=126(128), K=192; two N-halves ----
        #pragma unroll 1
        for (int half = 0; half < 2; ++half) {
            f32x4 c3[4][2];
            #pragma unroll
            for (int mt = 0; mt < 4; ++mt) { c3[mt][0] = vzero; c3[mt][1] = vzero; }
            f16x8 a3c[4];
            #pragma unroll
            for (int mt = 0; mt < 4; ++mt)
                a3c[mt] = *(const f16x8*)(w3row + (size_t)mt * 16 * 192);
            #pragma unroll 1
            for (int ks = 0; ks < 6; ++ks) {
                int t = ks >> 1, ich = ks & 1;
                f16x8 b3[2];
                #pragma unroll
                for (int jj = 0; jj < 2; ++jj) {
                    int np = ng * 64 + (half * 2 + jj) * 16 + l15;
                    int r = np + t; r = r < 128 ? r : 127;   // clamp (masked later)
                    int gq3 = ich * 4 + q4;
                    b3[jj] = *(const f16x8*)(&y2s[(r * 8 + (gq3 ^ (r & 7))) * 8]);
                }
                f16x8 a3n[4];
                if (ks < 5) {
                    #pragma unroll
                    for (int mt = 0; mt < 4; ++mt)
                        a3n[mt] = *(const f16x8*)(w3row + (size_t)mt * 16 * 192 + (ks + 1) * 32);
                }
                #pragma unroll
                for (int mt = 0; mt < 4; ++mt) {
                    c3[mt][0] = MFMA16(a3c[mt], b3[0], c3[mt][0]);
                    c3[mt][1] = MFMA16(a3c[mt], b3[1], c3[mt][1]);
                }
                if (ks < 5) {
                    #pragma unroll
                    for (int mt = 0; mt < 4; ++mt) a3c[mt] = a3n[mt];
                }
            }
            #pragma unroll
            for (int mt = 0; mt < 4; ++mt) {
                int oc0 = mg * 64 + mt * 16 + q4 * 4;
                #pragma unroll
                for (int jj = 0; jj < 2; ++jj) {
                    int np = ng * 64 + (half * 2 + jj) * 16 + l15;
                    int p3 = P0 + np;
                    float valf = ((np < 126) && (p3 < 1024)) ? 1.f : 0.f;
                    #pragma unroll
                    for (int r = 0; r < 4; ++r) {
                        float y = c3[mt][jj][r] + h3s[oc0 + r];
                        y = y > 0.f ? y : 0.f;
                        pool_[mt][r] = fmaf(y, valf, pool_[mt][r]);
                    }
                }
            }
        }
        __syncthreads();
    }

    // ---- pool: reduce over 16 n-lanes, combine waves via LDS, plain store ----
    #pragma unroll
    for (int mt = 0; mt < 4; ++mt)
        #pragma unroll
        for (int r = 0; r < 4; ++r) {
            float v = pool_[mt][r];
            v += __shfl_xor(v, 1, 64);
            v += __shfl_xor(v, 2, 64);
            v += __shfl_xor(v, 4, 64);
            v += __shfl_xor(v, 8, 64);
            if (l15 == 0) atomicAdd(&pbuf[mg * 64 + mt * 16 + q4 * 4 + r], v);
        }
    __syncthreads();
    if (tid < 128) pooled[g * 256 + br * 128 + tid] = pbuf[tid] * (1.f / 1024.f);
}

// ---------------------------------------------------------------------------
// K2: GAT -> f16 gat_out [g][1024]. One block per g.
// ---------------------------------------------------------------------------
__global__ __launch_bounds__(256) void gat_kernel(
    const float* __restrict__ glw, const float* __restrict__ att_src,
    const float* __restrict__ att_dst, const float* __restrict__ gbias,
    const float* __restrict__ pooled, _Float16* __restrict__ gouth)
{
    __shared__ float feats[256];
    __shared__ float hs[4 * 256];
    __shared__ float av[32];
    __shared__ float alpha[64];

    int g = blockIdx.x, tid = threadIdx.x;
    feats[tid] = pooled[g * 256 + tid];
    __syncthreads();

    { // h[n,o] = sum_c feat[n,c] * W[o,c]
        int o = tid;
        const float* w = glw + o * 64;
        float a0 = 0, a1 = 0, a2 = 0, a3 = 0;
        for (int c = 0; c < 64; ++c) {
            float wvv = w[c];
            a0 = fmaf(feats[c],       wvv, a0);
            a1 = fmaf(feats[64 + c],  wvv, a1);
            a2 = fmaf(feats[128 + c], wvv, a2);
            a3 = fmaf(feats[192 + c], wvv, a3);
        }
        hs[o] = a0; hs[256 + o] = a1; hs[512 + o] = a2; hs[768 + o] = a3;
    }
    __syncthreads();

    if (tid < 32) {
        int n = (tid & 15) >> 2, hd = tid & 3;
        const float* aw = (tid < 16) ? att_src : att_dst;
        float s = 0;
        for (int d = 0; d < 64; ++d) s = fmaf(hs[n * 256 + hd * 64 + d], aw[hd * 64 + d], s);
        av[tid] = s;
    }
    __syncthreads();

    if (tid < 16) {
        int i = tid >> 2, hd = tid & 3;
        float sc[4], mx = -1e30f;
        #pragma unroll
        for (int j = 0; j < 4; ++j) {
            float v = av[16 + i * 4 + hd] + av[j * 4 + hd];
            v = v > 0.f ? v : 0.2f * v;
            sc[j] = v; mx = fmaxf(mx, v);
        }
        float den = 0;
        #pragma unroll
        for (int j = 0; j < 4; ++j) { sc[j] = expf(sc[j] - mx); den += sc[j]; }
        #pragma unroll
        for (int j = 0; j < 4; ++j) alpha[(i * 4 + j) * 4 + hd] = sc[j] / den;
    }
    __syncthreads();

    { // gat_out[i,o] -> f16 global
        int o = tid, hd = o >> 6;
        #pragma unroll
        for (int i = 0; i < 4; ++i) {
            float acc = gbias[o];
            #pragma unroll
            for (int j = 0; j < 4; ++j) acc = fmaf(alpha[(i * 4 + j) * 4 + hd], hs[j * 256 + o], acc);
            gouth[(size_t)g * 1024 + i * 256 + o] = (_Float16)acc;
        }
    }
}

// ---------------------------------------------------------------------------
// MFMA GEMM: C[m][n] = A[m][K] . W[n][K] + bias.  Block tile 64x64, wave 16x64.
// MODE 0: f32 out.  MODE 1: relu -> f16 out.  MODE 3: +PE -> f32 + f16.
// ---------------------------------------------------------------------------
template <int K, int MODE>
__global__ __launch_bounds__(256) void mfma_gemm_kernel(
    const _Float16* __restrict__ A, const _Float16* __restrict__ W,
    const float* __restrict__ bias, float* __restrict__ out32,
    _Float16* __restrict__ out16, int N)
{
    const int tid = threadIdx.x;
    const int wv = tid >> 6, l15 = tid & 15, q4 = (tid & 63) >> 4;
    const int m0 = blockIdx.x * 64 + wv * 16;
    const int n0 = blockIdx.y * 64;

    const f32x4 vzero = {0.f, 0.f, 0.f, 0.f};
    f32x4 acc[4] = {vzero, vzero, vzero, vzero};

    const _Float16* arow = A + (size_t)(m0 + l15) * K + q4 * 8;
    #pragma unroll 4
    for (int ks = 0; ks < K / 32; ++ks) {
        f16x8 a = *(const f16x8*)(arow + ks * 32);
        #pragma unroll
        for (int nt = 0; nt < 4; ++nt) {
            f16x8 b = *(const f16x8*)(W + (size_t)(n0 + nt * 16 + l15) * K + ks * 32 + q4 * 8);
            acc[nt] = MFMA16(a, b, acc[nt]);
        }
    }

    #pragma unroll
    for (int nt = 0; nt < 4; ++nt) {
        int n = n0 + nt * 16 + l15;
        float bs = bias[n];
        #pragma unroll
        for (int r = 0; r < 4; ++r) {
            int m = m0 + q4 * 4 + r;
            float v = acc[nt][r] + bs;
            if (MODE == 1) v = fmaxf(v, 0.f);
            if (MODE == 3) {
                int s = m % 3;
                int kk = n >> 1;
                float dv = expf((float)kk * -0.07195588f);  // -2*ln(1e4)/256
                float arg = (float)s * dv;
                v += (n & 1) ? cosf(arg) : sinf(arg);
            }
            if (MODE == 0 || MODE == 3) out32[(size_t)m * N + n] = v;
            if (MODE == 1 || MODE == 3) out16[(size_t)m * N + n] = (_Float16)v;
        }
    }
}

// ---------------------------------------------------------------------------
// Fused MFMA GEMM (N=256) + bias + residual + LayerNorm.
// Block = 16 rows x 256 cols; wave tile 16x64. X is residual in, f32 out;
// XH f16 out. Grid = 48 blocks.
// ---------------------------------------------------------------------------
template <int K>
__global__ __launch_bounds__(256) void gemm_ln_kernel(
    const _Float16* __restrict__ A, const _Float16* __restrict__ W,
    const float* __restrict__ bias,
    const float* __restrict__ gamma, const float* __restrict__ beta,
    float* __restrict__ X, _Float16* __restrict__ XH)
{
    __shared__ float ys[16][260];
    const int tid = threadIdx.x;
    const int wv = tid >> 6, l15 = tid & 15, q4 = (tid & 63) >> 4;
    const int r0 = blockIdx.x * 16;
    const int n0 = wv * 64;

    const f32x4 vzero = {0.f, 0.f, 0.f, 0.f};
    f32x4 acc[4] = {vzero, vzero, vzero, vzero};

    const _Float16* arow = A + (size_t)(r0 + l15) * K + q4 * 8;
    #pragma unroll 4
    for (int ks = 0; ks < K / 32; ++ks) {
        f16x8 a = *(const f16x8*)(arow + ks * 32);
        #pragma unroll
        for (int nt = 0; nt < 4; ++nt) {
            f16x8 b = *(const f16x8*)(W + (size_t)(n0 + nt * 16 + l15) * K + ks * 32 + q4 * 8);
            acc[nt] = MFMA16(a, b, acc[nt]);
        }
    }

    #pragma unroll
    for (int nt = 0; nt < 4; ++nt) {
        int col = n0 + nt * 16 + l15;
        float bs = bias[col];
        #pragma unroll
        for (int r = 0; r < 4; ++r) {
            int rowl = q4 * 4 + r;
            ys[rowl][col] = acc[nt][r] + bs + X[(size_t)(r0 + rowl) * 256 + col];
        }
    }
    __syncthreads();

    {
        int row = tid >> 4, l16 = tid & 15;
        float s = 0, s2 = 0;
        #pragma unroll
        for (int c0 = 0; c0 < 256; c0 += 16) {
            float v = ys[row][c0 + l16]; s += v; s2 += v * v;
        }
        s += __shfl_xor(s, 1, 64);  s2 += __shfl_xor(s2, 1, 64);
        s += __shfl_xor(s, 2, 64);  s2 += __shfl_xor(s2, 2, 64);
        s += __shfl_xor(s, 4, 64);  s2 += __shfl_xor(s2, 4, 64);
        s += __shfl_xor(s, 8, 64);  s2 += __shfl_xor(s2, 8, 64);
        float mu = s * (1.f / 256.f);
        float var = s2 * (1.f / 256.f) - mu * mu;
        float inv = 1.0f / sqrtf(var + 1e-5f);
        #pragma unroll
        for (int c0 = 0; c0 < 256; c0 += 16) {
            int c = c0 + l16;
            float v = (ys[row][c] - mu) * inv * gamma[c] + beta[c];
            X[(size_t)(r0 + row) * 256 + c] = v;
            XH[(size_t)(r0 + row) * 256 + c] = (_Float16)v;
        }
    }
}

// ---------------------------------------------------------------------------
// Attention: S=3, one block per batch b, one wave per head. f32 in, f16 out.
// ---------------------------------------------------------------------------
__global__ __launch_bounds__(256) void attn_kernel(
    const float* __restrict__ qkv, _Float16* __restrict__ abufh)
{
    int b = blockIdx.x, tid = threadIdx.x, head = tid >> 6, d = tid & 63;
    const float* base = qkv + (size_t)b * 3 * 768 + head * 64 + d;
    float q[3], k[3], v[3];
    #pragma unroll
    for (int s = 0; s < 3; ++s) {
        const float* row = base + s * 768;
        q[s] = row[0]; k[s] = row[256]; v[s] = row[512];
    }
    float sc[3][3];
    #pragma unroll
    for (int si = 0; si < 3; ++si)
        #pragma unroll
        for (int sj = 0; sj < 3; ++sj) {
            float p = q[si] * k[sj];
            #pragma unroll
            for (int m = 32; m > 0; m >>= 1) p += __shfl_xor(p, m, 64);
            sc[si][sj] = p * 0.125f;
        }
    #pragma unroll
    for (int si = 0; si < 3; ++si) {
        float mx = fmaxf(sc[si][0], fmaxf(sc[si][1], sc[si][2]));
        float e0 = expf(sc[si][0] - mx), e1 = expf(sc[si][1] - mx), e2 = expf(sc[si][2] - mx);
        float den = e0 + e1 + e2;
        float o = (e0 * v[0] + e1 * v[1] + e2 * v[2]) / den;
        abufh[(size_t)(b * 3 + si) * 256 + head * 64 + d] = (_Float16)o;
    }
}

// ---------------------------------------------------------------------------
// Head: temporal attention + fc1/relu + fc2/relu + fc3. One block per b.
// ---------------------------------------------------------------------------
__global__ __launch_bounds__(256) void head_kernel(
    const float* __restrict__ X, const float* __restrict__ taw, const float* __restrict__ tab,
    const float* __restrict__ f1w, const float* __restrict__ f1b,
    const float* __restrict__ f2w, const float* __restrict__ f2b,
    const float* __restrict__ f3w, const float* __restrict__ f3b,
    float* __restrict__ out)
{
    __shared__ float xs[3 * 256];
    __shared__ float wsm[3];
    __shared__ float cs[256];
    __shared__ float a1[128];
    __shared__ float a2[64];
    int b = blockIdx.x, tid = threadIdx.x;
    for (int idx = tid; idx < 768; idx += 256) xs[idx] = X[(size_t)b * 768 + idx];
    __syncthreads();
    if (tid < 3) {
        float s = tab[0];
        for (int d = 0; d < 256; ++d) s = fmaf(xs[tid * 256 + d], taw[d], s);
        wsm[tid] = s;
    }
    __syncthreads();
    {
        float m = fmaxf(wsm[0], fmaxf(wsm[1], wsm[2]));
        float e0 = expf(wsm[0] - m), e1 = expf(wsm[1] - m), e2 = expf(wsm[2] - m);
        float den = e0 + e1 + e2;
        cs[tid] = (e0 * xs[tid] + e1 * xs[256 + tid] + e2 * xs[512 + tid]) / den;
    }
    __syncthreads();
    if (tid < 128) {
        float a = f1b[tid];
        const float* w = f1w + tid * 256;
        for (int c = 0; c < 256; ++c) a = fmaf(cs[c], w[c], a);
        a1[tid] = fmaxf(a, 0.f);
    }
    __syncthreads();
    if (tid < 64) {
        float a = f2b[tid];
        const float* w = f2w + tid * 128;
        for (int c = 0; c < 128; ++c) a = fmaf(a1[c], w[c], a);
        a2[tid] = fmaxf(a, 0.f);
    }
    __syncthreads();
    if (tid < 5) {
        float a = f3b[tid];
        const float* w = f3w + tid * 64;
        for (int c = 0; c < 64; ++c) a = fmaf(a2[c], w[c], a);
        out[b * 5 + tid] = a;
    }
}

// ---------------------------------------------------------------------------
extern "C" void kernel_launch(void* const* d_in, const int* in_sizes, int n_in,
                              void* d_out, int out_size, void* d_ws, size_t ws_size,
                              hipStream_t stream) {
    const float* x_t     = (const float*)d_in[0];
    const float* x_f     = (const float*)d_in[1];
    const float* conv1_w = (const float*)d_in[2];
    const float* conv1_b = (const float*)d_in[3];
    const float* bn1_g   = (const float*)d_in[4];
    const float* bn1_b   = (const float*)d_in[5];
    const float* bn1_m   = (const float*)d_in[6];
    const float* bn1_v   = (const float*)d_in[7];
    const float* conv2_w = (const float*)d_in[8];
    const float* conv2_b = (const float*)d_in[9];
    const float* bn2_g   = (const float*)d_in[10];
    const float* bn2_b   = (const float*)d_in[11];
    const float* bn2_m   = (const float*)d_in[12];
    const float* bn2_v   = (const float*)d_in[13];
    const float* conv3_w = (const float*)d_in[14];
    const float* conv3_b = (const float*)d_in[15];
    const float* bn3_g   = (const float*)d_in[16];
    const float* bn3_b   = (const float*)d_in[17];
    const float* bn3_m   = (const float*)d_in[18];
    const float* bn3_v   = (const float*)d_in[19];
    const float* gat_lin_w   = (const float*)d_in[20];
    const float* gat_att_src = (const float*)d_in[21];
    const float* gat_att_dst = (const float*)d_in[22];
    const float* gat_bias    = (const float*)d_in[23];
    const float* feat_proj_w = (const float*)d_in[24];
    const float* feat_proj_b = (const float*)d_in[25];
    const float* tr_in_w  = (const float*)d_in[26];
    const float* tr_in_b  = (const float*)d_in[27];
    const float* tr_out_w = (const float*)d_in[28];
    const float* tr_out_b = (const float*)d_in[29];
    const float* tr_l1_w  = (const float*)d_in[30];
    const float* tr_l1_b  = (const float*)d_in[31];
    const float* tr_l2_w  = (const float*)d_in[32];
    const float* tr_l2_b  = (const float*)d_in[33];
    const float* tr_ln1_g = (const float*)d_in[34];
    const float* tr_ln1_b = (const float*)d_in[35];
    const float* tr_ln2_g = (const float*)d_in[36];
    const float* tr_ln2_b = (const float*)d_in[37];
    const float* ta_w  = (const float*)d_in[38];
    const float* ta_b  = (const float*)d_in[39];
    const float* fc1_w = (const float*)d_in[40];
    const float* fc1_b = (const float*)d_in[41];
    const float* fc2_w = (const float*)d_in[42];
    const float* fc2_b = (const float*)d_in[43];
    const float* fc3_w = (const float*)d_in[44];
    const float* fc3_b = (const float*)d_in[45];

    float* ws    = (float*)d_ws;
    float* POOL  = ws + WS_POOL;
    float* X     = ws + WS_X;
    float* QKV   = ws + WS_SCR;                    // f32 [768][768]
    _Float16* GOUTH = (_Float16*)(ws + WS_SCR);    // f16 [768][1024]
    _Float16* MIDH  = (_Float16*)(ws + WS_SCR);    // f16 [768][1024]
    _Float16* XH    = (_Float16*)(ws + WS_XH);
    _Float16* ABH   = (_Float16*)(ws + WS_ABH);
    const _Float16* FPWH  = (const _Float16*)(ws + WS_FPWH);
    const _Float16* INWH  = (const _Float16*)(ws + WS_INWH);
    const _Float16* OUTWH = (const _Float16*)(ws + WS_OUTWH);
    const _Float16* L1WH  = (const _Float16*)(ws + WS_L1WH);
    const _Float16* L2WH  = (const _Float16*)(ws + WS_L2WH);
    float* out = (float*)d_out;

    prep_kernel<<<192, 256, 0, stream>>>(conv1_w, conv2_w, conv3_w,
        conv1_b, bn1_g, bn1_b, bn1_m, bn1_v,
        conv2_b, bn2_g, bn2_b, bn2_m, bn2_v,
        conv3_b, bn3_g, bn3_b, bn3_m, bn3_v, ws);
    prep_tr_kernel<<<2048, 256, 0, stream>>>(feat_proj_w, tr_in_w, tr_out_w,
                                             tr_l1_w, tr_l2_w, ws);

    conv_mfma_kernel<<<dim3(Gn, 2), 256, 0, stream>>>(x_t, x_f, ws, POOL);

    gat_kernel<<<Gn, 256, 0, stream>>>(gat_lin_w, gat_att_src, gat_att_dst, gat_bias,
                                       POOL, GOUTH);

    // feat_proj + PE: X = GOUTH @ fpw^T + fpb + pe   (M=768, K=1024, N=256)
    mfma_gemm_kernel<1024, 3><<<dim3(12, 4), 256, 0, stream>>>(
        GOUTH, FPWH, feat_proj_b, X, XH, 256);

    for (int l = 0; l < TLn; ++l) {
        mfma_gemm_kernel<256, 0><<<dim3(12, 12), 256, 0, stream>>>(
            XH, INWH + (size_t)l * 196608, tr_in_b + l * 768, QKV, nullptr, 768);
        attn_kernel<<<Bn, 256, 0, stream>>>(QKV, ABH);
        gemm_ln_kernel<256><<<48, 256, 0, stream>>>(
            ABH, OUTWH + (size_t)l * 65536, tr_out_b + l * 256,
            tr_ln1_g + l * 256, tr_ln1_b + l * 256, X, XH);
        mfma_gemm_kernel<256, 1><<<dim3(12, 16), 256, 0, stream>>>(
            XH, L1WH + (size_t)l * 262144, tr_l1_b + l * 1024, nullptr, MIDH, 1024);
        gemm_ln_kernel<1024><<<48, 256, 0, stream>>>(
            MIDH, L2WH + (size_t)l * 262144, tr_l2_b + l * 256,
            tr_ln2_g + l * 256, tr_ln2_b + l * 256, X, XH);
    }

    head_kernel<<<Bn, 256, 0, stream>>>(X, ta_w, ta_b, fc1_w, fc1_b,
                                        fc2_w, fc2_b, fc3_w, fc3_b, out);
}

// Round 6
// 776.889 us; speedup vs baseline: 1.1365x; 1.1365x over previous
//
#include <hip/hip_runtime.h>
#include <math.h>

// ---------------------------------------------------------------------------
// Sizes
// ---------------------------------------------------------------------------
#define Bn 256
#define Sn 3
#define Ln 4096
#define Gn 768          // B*S
#define TDn 256
#define TLn 2

// Workspace layout (float offsets)
#define WS_W1K   0        // 1024 fl  (2048 f16)   [br][oc32][k32]
#define WS_W2K   1024     // 14336 fl (28672 f16)  [br][oc64][k224]
#define WS_W3K   15360    // 24576 fl (49152 f16)  [br][oc128][k192]
#define WS_H1    39936    // 64
#define WS_H2    40000    // 128
#define WS_H3    40128    // 256
#define WS_FPWH  40960    // 131072 fl = 262144 f16  fpw [256][1024]
#define WS_INWH  172032   // 196608 fl = 393216 f16  [TL][768][256]
#define WS_OUTWH 368640   // 65536 fl  = 131072 f16  [TL][256][256]
#define WS_L1WH  434176   // 262144 fl = 524288 f16  [TL][1024][256]
#define WS_L2WH  696320   // 262144 fl = 524288 f16  [TL][256][1024]
#define WS_POOL  958464   // 196608 fl f32 [768][256]  (dead after gat ->)
#define WS_XH    958464   //   98304 fl = 196608 f16 [768][256]
#define WS_ABH   1056768  //   98304 fl = 196608 f16 [768][256]
#define WS_SCR   1155072  // 589824 fl: GOUTH f16[768][1024] | QKV f32[768][768] | MIDH f16[768][1024]
#define WS_Y     1548288  // 196608 fl (unused)
#define WS_X     1744896  // 196608 fl f32 [768][256]
// end: 1941504 floats = 7.77 MB

typedef _Float16 f16x8 __attribute__((ext_vector_type(8)));
typedef float f32x4 __attribute__((ext_vector_type(4)));
#define MFMA16(a,b,c) __builtin_amdgcn_mfma_f32_16x16x32_f16(a,b,c,0,0,0)

// ---------------------------------------------------------------------------
// K0a: conv weight transpose to f16 + BN fold
// ---------------------------------------------------------------------------
__global__ __launch_bounds__(256) void prep_kernel(
    const float* __restrict__ w1, const float* __restrict__ w2, const float* __restrict__ w3,
    const float* __restrict__ c1b, const float* __restrict__ g1, const float* __restrict__ b1,
    const float* __restrict__ m1, const float* __restrict__ v1,
    const float* __restrict__ c2b, const float* __restrict__ g2, const float* __restrict__ b2,
    const float* __restrict__ m2, const float* __restrict__ v2,
    const float* __restrict__ c3b, const float* __restrict__ g3, const float* __restrict__ b3,
    const float* __restrict__ m3, const float* __restrict__ v3,
    float* __restrict__ ws)
{
    int i = blockIdx.x * 256 + threadIdx.x;
    _Float16* w1k = (_Float16*)(ws + WS_W1K);
    _Float16* w2k = (_Float16*)(ws + WS_W2K);
    _Float16* w3k = (_Float16*)(ws + WS_W3K);
    if (i < 2048) { // i = (br*32+oc)*32 + c*16+tau
        int k = i & 31, oc = (i >> 5) & 31, br = i >> 10;
        int c = k >> 4, tau = k & 15;
        int a = br * 32 + oc;
        float s = g1[a] / sqrtf(v1[a] + 1e-5f);
        float v = (tau < 15) ? w1[(((size_t)a * 2 + c) * 15) + tau] * s : 0.f;
        w1k[i] = (_Float16)v;
    }
    if (i < 28672) { // i = (br*64+oc)*224 + tblk*32+ic
        int k = i % 224; int a = i / 224;
        int tblk = k >> 5, ic = k & 31;
        int t = (tblk < 4) ? 2 * tblk : 2 * (tblk - 4) + 1;
        float s = g2[a] / sqrtf(v2[a] + 1e-5f);
        w2k[i] = (_Float16)(w2[((size_t)a * 32 + ic) * 7 + t] * s);
    }
    if (i < 49152) { // i = (br*128+oc)*192 + t*64+ic
        int k = i % 192; int a = i / 192;
        int t = k >> 6, ic = k & 63;
        float s = g3[a] / sqrtf(v3[a] + 1e-5f);
        w3k[i] = (_Float16)(w3[((size_t)a * 64 + ic) * 3 + t] * s);
    }
    if (i < 64)  { float s = g1[i] / sqrtf(v1[i] + 1e-5f); ws[WS_H1 + i] = (c1b[i] - m1[i]) * s + b1[i]; }
    if (i < 128) { float s = g2[i] / sqrtf(v2[i] + 1e-5f); ws[WS_H2 + i] = (c2b[i] - m2[i]) * s + b2[i]; }
    if (i < 256) { float s = g3[i] / sqrtf(v3[i] + 1e-5f); ws[WS_H3 + i] = (c3b[i] - m3[i]) * s + b3[i]; }
}

// ---------------------------------------------------------------------------
// K0b: transformer / feat_proj weights -> f16 (layouts already [N][K])
// ---------------------------------------------------------------------------
__global__ __launch_bounds__(256) void prep_tr_kernel(
    const float* __restrict__ fpw, const float* __restrict__ inw,
    const float* __restrict__ outw, const float* __restrict__ l1w,
    const float* __restrict__ l2w, float* __restrict__ ws)
{
    int i = blockIdx.x * 256 + threadIdx.x;
    _Float16* fpwh = (_Float16*)(ws + WS_FPWH);
    _Float16* inwh = (_Float16*)(ws + WS_INWH);
    _Float16* outwh = (_Float16*)(ws + WS_OUTWH);
    _Float16* l1wh = (_Float16*)(ws + WS_L1WH);
    _Float16* l2wh = (_Float16*)(ws + WS_L2WH);
    if (i < 262144) fpwh[i] = (_Float16)fpw[i];
    if (i < 393216) inwh[i] = (_Float16)inw[i];
    if (i < 131072) outwh[i] = (_Float16)outw[i];
    if (i < 524288) { l1wh[i] = (_Float16)l1w[i]; l2wh[i] = (_Float16)l2w[i]; }
}

// ---------------------------------------------------------------------------
// K1: fused conv1->conv2->conv3->mean-pool via fp16 MFMA.
// Round-6: __launch_bounds__(256,3) (170-reg budget; (256,2) gave 2 blk/CU
// @449us, (256,4) re-spilled @592us). Live set shrunk below the cap:
//  - no a2n/a3n double-buffer prefetch (inter-wave overlap at 3 blk/CU
//    hides the per-ks L2 weight latency instead)
//  - conv2 jj passes merged (halves conv2 weight refetch vs round 5)
// Keep: unroll-1 K-loops (anti-hoist, the round-4 spill fix), LDS pbuf pool.
// ---------------------------------------------------------------------------
__global__ __launch_bounds__(256, 3) void conv_mfma_kernel(
    const float* __restrict__ x_t, const float* __restrict__ x_f,
    const float* __restrict__ ws, float* __restrict__ pooled)
{
    __shared__ _Float16 xsf[2 * 576];       // [c][l], f16
    __shared__ _Float16 y1[2][132 * 32];    // [parity][row i][ic granule-swizzled]
    __shared__ _Float16 y2s[128 * 64];      // [row n][oc granule-swizzled]
    __shared__ float h1s[32];
    __shared__ float h2s[64];
    __shared__ float h3s[128];
    __shared__ float pbuf[128];

    const int g = blockIdx.x, br = blockIdx.y;
    const int tid = threadIdx.x;
    const int lane = tid & 63, wv = tid >> 6;
    const int l15 = lane & 15, q4 = lane >> 4;

    const float* xin = (br == 0 ? x_t : x_f) + (size_t)g * (Ln * 2);
    const _Float16* w1k = (const _Float16*)(ws + WS_W1K) + br * 1024;
    const _Float16* w2k = (const _Float16*)(ws + WS_W2K) + br * 14336;
    const _Float16* w3k = (const _Float16*)(ws + WS_W3K) + br * 24576;

    if (tid < 32)  h1s[tid] = ws[WS_H1 + br * 32 + tid];
    if (tid < 64)  h2s[tid] = ws[WS_H2 + br * 64 + tid];
    if (tid < 128) { h3s[tid] = ws[WS_H3 + br * 128 + tid]; pbuf[tid] = 0.f; }

    // conv1 A-frags (weights, resident, 8 VGPRs): A[m=l15][k=q4*8+j]
    f16x8 a1[2];
    #pragma unroll
    for (int mt = 0; mt < 2; ++mt)
        a1[mt] = *(const f16x8*)(w1k + (mt * 16 + l15) * 32 + q4 * 8);

    const int mg = wv & 1, ng = wv >> 1;

    // per-wave weight row bases
    const _Float16* w2row = w2k + (size_t)l15 * 224 + q4 * 8;
    const _Float16* w3row = w3k + (size_t)(mg * 64 + l15) * 192 + q4 * 8;

    float pool_[4][4];
    #pragma unroll
    for (int mt = 0; mt < 4; ++mt)
        #pragma unroll
        for (int r = 0; r < 4; ++r) pool_[mt][r] = 0.f;

    const f32x4 vzero = {0.f, 0.f, 0.f, 0.f};

    #pragma unroll 1
    for (int tile = 0; tile < 9; ++tile) {
        const int P0 = tile * 126;
        const int Q0 = 2 * P0 - 5;
        const int x0 = 4 * P0 - 17;

        // ---- stage x slice -> f16 LDS ----
        for (int l = tid; l < 576; l += 256) {
            int xl = x0 + l;
            float a = 0.f, b = 0.f;
            if (xl >= 0 && xl < Ln) { float2 v = *(const float2*)(xin + (size_t)xl * 2); a = v.x; b = v.y; }
            xsf[l] = (_Float16)a; xsf[576 + l] = (_Float16)b;
        }
        __syncthreads();

        // ---- conv1 MFMA: M=32 (2 tiles), N=261 (17 tiles), K=32 ----
        const uint* xsu = (const uint*)xsf;
        #pragma unroll 1
        for (int nt = wv; nt < 17; nt += 4) {
            int j0 = nt * 16 + l15;
            union { f16x8 v; uint u[4]; } bf;
            int ubase = (q4 >> 1) * 288 + j0 + (q4 & 1) * 4;
            #pragma unroll
            for (int ii = 0; ii < 4; ++ii) bf.u[ii] = xsu[ubase + ii];
            f32x4 c1acc[2] = {vzero, vzero};
            c1acc[0] = MFMA16(a1[0], bf.v, c1acc[0]);
            c1acc[1] = MFMA16(a1[1], bf.v, c1acc[1]);

            if (j0 <= 260) {
                int q = Q0 + j0;
                bool val = (q >= 0) && (q < 2048);
                int i = j0 >> 1, par = j0 & 1;
                #pragma unroll
                for (int mt = 0; mt < 2; ++mt) {
                    int oc0 = mt * 16 + q4 * 4;
                    union { _Float16 h[4]; uint2 u; } pk;
                    #pragma unroll
                    for (int r = 0; r < 4; ++r) {
                        float y = c1acc[mt][r] + h1s[oc0 + r];
                        y = y > 0.f ? y : 0.f;
                        pk.h[r] = val ? (_Float16)y : (_Float16)0.f;
                    }
                    int gq = mt * 2 + (q4 >> 1), sub = q4 & 1;
                    *(uint2*)(&y1[par][(i * 4 + (gq ^ (i & 3))) * 8 + sub * 4]) = pk.u;
                }
            }
        }
        __syncthreads();

        // ---- conv2 MFMA: M=64 (4 tiles), N=128 (wave owns 32), K=224 ----
        // single-buffered weight loads inside unroll-1 ks loop
        {
            f32x4 c2[4][2];
            #pragma unroll
            for (int mt = 0; mt < 4; ++mt) { c2[mt][0] = vzero; c2[mt][1] = vzero; }
            #pragma unroll 1
            for (int ks = 0; ks < 7; ++ks) {
                int roff = (ks < 4) ? ks : ks - 4;
                const _Float16* yb = y1[(ks < 4) ? 0 : 1];
                f16x8 a2f[4];
                #pragma unroll
                for (int mt = 0; mt < 4; ++mt)
                    a2f[mt] = *(const f16x8*)(w2row + (size_t)mt * 16 * 224 + ks * 32);
                f16x8 bb[2];
                #pragma unroll
                for (int jj = 0; jj < 2; ++jj) {
                    int n = wv * 32 + jj * 16 + l15;
                    int i = n + roff;
                    bb[jj] = *(const f16x8*)(yb + (i * 4 + (q4 ^ (i & 3))) * 8);
                }
                #pragma unroll
                for (int mt = 0; mt < 4; ++mt) {
                    c2[mt][0] = MFMA16(a2f[mt], bb[0], c2[mt][0]);
                    c2[mt][1] = MFMA16(a2f[mt], bb[1], c2[mt][1]);
                }
            }
            #pragma unroll
            for (int jj = 0; jj < 2; ++jj) {
                int n = wv * 32 + jj * 16 + l15;
                int p2 = P0 - 1 + n;
                bool val = (p2 >= 0) && (p2 < 1024);
                #pragma unroll
                for (int mt = 0; mt < 4; ++mt) {
                    int oc0 = mt * 16 + q4 * 4;
                    union { _Float16 h[4]; uint2 u; } pk;
                    #pragma unroll
                    for (int r = 0; r < 4; ++r) {
                        float y = c2[mt][jj][r] + h2s[oc0 + r];
                        y = y > 0.f ? y : 0.f;
                        pk.h[r] = val ? (_Float16)y : (_Float16)0.f;
                    }
                    int gq = oc0 >> 3, sub = q4 & 1;
                    *(uint2*)(&y2s[(n * 8 + (gq ^ (n & 7))) * 8 + sub * 4]) = pk.u;
                }
            }
        }
        __syncthreads();

        // ---- conv3 MFMA + pool: M=128, N=126(128), K=192; two N-halves ----
        #pragma unroll 1
        for (int half = 0; half < 2; ++half) {
            f32x4 c3[4][2];
            #pragma unroll
            for (int mt = 0; mt < 4; ++mt) { c3[mt][0] = vzero; c3[mt][1] = vzero; }
            #pragma unroll 1
            for (int ks = 0; ks < 6; ++ks) {
                int t = ks >> 1, ich = ks & 1;
                f16x8 a3f[4];
                #pragma unroll
                for (int mt = 0; mt < 4; ++mt)
                    a3f[mt] = *(const f16x8*)(w3row + (size_t)mt * 16 * 192 + ks * 32);
                f16x8 b3[2];
                #pragma unroll
                for (int jj = 0; jj < 2; ++jj) {
                    int np = ng * 64 + (half * 2 + jj) * 16 + l15;
                    int r = np + t; r = r < 128 ? r : 127;   // clamp (masked later)
                    int gq3 = ich * 4 + q4;
                    b3[jj] = *(const f16x8*)(&y2s[(r * 8 + (gq3 ^ (r & 7))) * 8]);
                }
                #pragma unroll
                for (int mt = 0; mt < 4; ++mt) {
                    c3[mt][0] = MFMA16(a3f[mt], b3[0], c3[mt][0]);
                    c3[mt][1] = MFMA16(a3f[mt], b3[1], c3[mt][1]);
                }
            }
            #pragma unroll
            for (int mt = 0; mt < 4; ++mt) {
                int oc0 = mg * 64 + mt * 16 + q4 * 4;
                #pragma unroll
                for (int jj = 0; jj < 2; ++jj) {
                    int np = ng * 64 + (half * 2 + jj) * 16 + l15;
                    int p3 = P0 + np;
                    float valf = ((np < 126) && (p3 < 1024)) ? 1.f : 0.f;
                    #pragma unroll
                    for (int r = 0; r < 4; ++r) {
                        float y = c3[mt][jj][r] + h3s[oc0 + r];
                        y = y > 0.f ? y : 0.f;
                        pool_[mt][r] = fmaf(y, valf, pool_[mt][r]);
                    }
                }
            }
        }
        __syncthreads();
    }

    // ---- pool: reduce over 16 n-lanes, combine waves via LDS, plain store ----
    #pragma unroll
    for (int mt = 0; mt < 4; ++mt)
        #pragma unroll
        for (int r = 0; r < 4; ++r) {
            float v = pool_[mt][r];
            v += __shfl_xor(v, 1, 64);
            v += __shfl_xor(v, 2, 64);
            v += __shfl_xor(v, 4, 64);
            v += __shfl_xor(v, 8, 64);
            if (l15 == 0) atomicAdd(&pbuf[mg * 64 + mt * 16 + q4 * 4 + r], v);
        }
    __syncthreads();
    if (tid < 128) pooled[g * 256 + br * 128 + tid] = pbuf[tid] * (1.f / 1024.f);
}

// ---------------------------------------------------------------------------
// K2: GAT -> f16 gat_out [g][1024]. One block per g.
// ---------------------------------------------------------------------------
__global__ __launch_bounds__(256) void gat_kernel(
    const float* __restrict__ glw, const float* __restrict__ att_src,
    const float* __restrict__ att_dst, const float* __restrict__ gbias,
    const float* __restrict__ pooled, _Float16* __restrict__ gouth)
{
    __shared__ float feats[256];
    __shared__ float hs[4 * 256];
    __shared__ float av[32];
    __shared__ float alpha[64];

    int g = blockIdx.x, tid = threadIdx.x;
    feats[tid] = pooled[g * 256 + tid];
    __syncthreads();

    { // h[n,o] = sum_c feat[n,c] * W[o,c]
        int o = tid;
        const float* w = glw + o * 64;
        float a0 = 0, a1 = 0, a2 = 0, a3 = 0;
        for (int c = 0; c < 64; ++c) {
            float wvv = w[c];
            a0 = fmaf(feats[c],       wvv, a0);
            a1 = fmaf(feats[64 + c],  wvv, a1);
            a2 = fmaf(feats[128 + c], wvv, a2);
            a3 = fmaf(feats[192 + c], wvv, a3);
        }
        hs[o] = a0; hs[256 + o] = a1; hs[512 + o] = a2; hs[768 + o] = a3;
    }
    __syncthreads();

    if (tid < 32) {
        int n = (tid & 15) >> 2, hd = tid & 3;
        const float* aw = (tid < 16) ? att_src : att_dst;
        float s = 0;
        for (int d = 0; d < 64; ++d) s = fmaf(hs[n * 256 + hd * 64 + d], aw[hd * 64 + d], s);
        av[tid] = s;
    }
    __syncthreads();

    if (tid < 16) {
        int i = tid >> 2, hd = tid & 3;
        float sc[4], mx = -1e30f;
        #pragma unroll
        for (int j = 0; j < 4; ++j) {
            float v = av[16 + i * 4 + hd] + av[j * 4 + hd];
            v = v > 0.f ? v : 0.2f * v;
            sc[j] = v; mx = fmaxf(mx, v);
        }
        float den = 0;
        #pragma unroll
        for (int j = 0; j < 4; ++j) { sc[j] = expf(sc[j] - mx); den += sc[j]; }
        #pragma unroll
        for (int j = 0; j < 4; ++j) alpha[(i * 4 + j) * 4 + hd] = sc[j] / den;
    }
    __syncthreads();

    { // gat_out[i,o] -> f16 global
        int o = tid, hd = o >> 6;
        #pragma unroll
        for (int i = 0; i < 4; ++i) {
            float acc = gbias[o];
            #pragma unroll
            for (int j = 0; j < 4; ++j) acc = fmaf(alpha[(i * 4 + j) * 4 + hd], hs[j * 256 + o], acc);
            gouth[(size_t)g * 1024 + i * 256 + o] = (_Float16)acc;
        }
    }
}

// ---------------------------------------------------------------------------
// MFMA GEMM: C[m][n] = A[m][K] . W[n][K] + bias.  Block tile 64x64, wave 16x64.
// MODE 0: f32 out.  MODE 1: relu -> f16 out.  MODE 3: +PE -> f32 + f16.
// ---------------------------------------------------------------------------
template <int K, int MODE>
__global__ __launch_bounds__(256) void mfma_gemm_kernel(
    const _Float16* __restrict__ A, const _Float16* __restrict__ W,
    const float* __restrict__ bias, float* __restrict__ out32,
    _Float16* __restrict__ out16, int N)
{
    const int tid = threadIdx.x;
    const int wv = tid >> 6, l15 = tid & 15, q4 = (tid & 63) >> 4;
    const int m0 = blockIdx.x * 64 + wv * 16;
    const int n0 = blockIdx.y * 64;

    const f32x4 vzero = {0.f, 0.f, 0.f, 0.f};
    f32x4 acc[4] = {vzero, vzero, vzero, vzero};

    const _Float16* arow = A + (size_t)(m0 + l15) * K + q4 * 8;
    #pragma unroll 4
    for (int ks = 0; ks < K / 32; ++ks) {
        f16x8 a = *(const f16x8*)(arow + ks * 32);
        #pragma unroll
        for (int nt = 0; nt < 4; ++nt) {
            f16x8 b = *(const f16x8*)(W + (size_t)(n0 + nt * 16 + l15) * K + ks * 32 + q4 * 8);
            acc[nt] = MFMA16(a, b, acc[nt]);
        }
    }

    #pragma unroll
    for (int nt = 0; nt < 4; ++nt) {
        int n = n0 + nt * 16 + l15;
        float bs = bias[n];
        #pragma unroll
        for (int r = 0; r < 4; ++r) {
            int m = m0 + q4 * 4 + r;
            float v = acc[nt][r] + bs;
            if (MODE == 1) v = fmaxf(v, 0.f);
            if (MODE == 3) {
                int s = m % 3;
                int kk = n >> 1;
                float dv = expf((float)kk * -0.07195588f);  // -2*ln(1e4)/256
                float arg = (float)s * dv;
                v += (n & 1) ? cosf(arg) : sinf(arg);
            }
            if (MODE == 0 || MODE == 3) out32[(size_t)m * N + n] = v;
            if (MODE == 1 || MODE == 3) out16[(size_t)m * N + n] = (_Float16)v;
        }
    }
}

// ---------------------------------------------------------------------------
// Fused MFMA GEMM (N=256) + bias + residual + LayerNorm.
// Block = 16 rows x 256 cols; wave tile 16x64. Grid = 48 blocks.
// ---------------------------------------------------------------------------
template <int K>
__global__ __launch_bounds__(256) void gemm_ln_kernel(
    const _Float16* __restrict__ A, const _Float16* __restrict__ W,
    const float* __restrict__ bias,
    const float* __restrict__ gamma, const float* __restrict__ beta,
    float* __restrict__ X, _Float16* __restrict__ XH)
{
    __shared__ float ys[16][260];
    const int tid = threadIdx.x;
    const int wv = tid >> 6, l15 = tid & 15, q4 = (tid & 63) >> 4;
    const int r0 = blockIdx.x * 16;
    const int n0 = wv * 64;

    const f32x4 vzero = {0.f, 0.f, 0.f, 0.f};
    f32x4 acc[4] = {vzero, vzero, vzero, vzero};

    const _Float16* arow = A + (size_t)(r0 + l15) * K + q4 * 8;
    #pragma unroll 4
    for (int ks = 0; ks < K / 32; ++ks) {
        f16x8 a = *(const f16x8*)(arow + ks * 32);
        #pragma unroll
        for (int nt = 0; nt < 4; ++nt) {
            f16x8 b = *(const f16x8*)(W + (size_t)(n0 + nt * 16 + l15) * K + ks * 32 + q4 * 8);
            acc[nt] = MFMA16(a, b, acc[nt]);
        }
    }

    #pragma unroll
    for (int nt = 0; nt < 4; ++nt) {
        int col = n0 + nt * 16 + l15;
        float bs = bias[col];
        #pragma unroll
        for (int r = 0; r < 4; ++r) {
            int rowl = q4 * 4 + r;
            ys[rowl][col] = acc[nt][r] + bs + X[(size_t)(r0 + rowl) * 256 + col];
        }
    }
    __syncthreads();

    {
        int row = tid >> 4, l16 = tid & 15;
        float s = 0, s2 = 0;
        #pragma unroll
        for (int c0 = 0; c0 < 256; c0 += 16) {
            float v = ys[row][c0 + l16]; s += v; s2 += v * v;
        }
        s += __shfl_xor(s, 1, 64);  s2 += __shfl_xor(s2, 1, 64);
        s += __shfl_xor(s, 2, 64);  s2 += __shfl_xor(s2, 2, 64);
        s += __shfl_xor(s, 4, 64);  s2 += __shfl_xor(s2, 4, 64);
        s += __shfl_xor(s, 8, 64);  s2 += __shfl_xor(s2, 8, 64);
        float mu = s * (1.f / 256.f);
        float var = s2 * (1.f / 256.f) - mu * mu;
        float inv = 1.0f / sqrtf(var + 1e-5f);
        #pragma unroll
        for (int c0 = 0; c0 < 256; c0 += 16) {
            int c = c0 + l16;
            float v = (ys[row][c] - mu) * inv * gamma[c] + beta[c];
            X[(size_t)(r0 + row) * 256 + c] = v;
            XH[(size_t)(r0 + row) * 256 + c] = (_Float16)v;
        }
    }
}

// ---------------------------------------------------------------------------
// Attention: S=3, one block per batch b, one wave per head. f32 in, f16 out.
// ---------------------------------------------------------------------------
__global__ __launch_bounds__(256) void attn_kernel(
    const float* __restrict__ qkv, _Float16* __restrict__ abufh)
{
    int b = blockIdx.x, tid = threadIdx.x, head = tid >> 6, d = tid & 63;
    const float* base = qkv + (size_t)b * 3 * 768 + head * 64 + d;
    float q[3], k[3], v[3];
    #pragma unroll
    for (int s = 0; s < 3; ++s) {
        const float* row = base + s * 768;
        q[s] = row[0]; k[s] = row[256]; v[s] = row[512];
    }
    float sc[3][3];
    #pragma unroll
    for (int si = 0; si < 3; ++si)
        #pragma unroll
        for (int sj = 0; sj < 3; ++sj) {
            float p = q[si] * k[sj];
            #pragma unroll
            for (int m = 32; m > 0; m >>= 1) p += __shfl_xor(p, m, 64);
            sc[si][sj] = p * 0.125f;
        }
    #pragma unroll
    for (int si = 0; si < 3; ++si) {
        float mx = fmaxf(sc[si][0], fmaxf(sc[si][1], sc[si][2]));
        float e0 = expf(sc[si][0] - mx), e1 = expf(sc[si][1] - mx), e2 = expf(sc[si][2] - mx);
        float den = e0 + e1 + e2;
        float o = (e0 * v[0] + e1 * v[1] + e2 * v[2]) / den;
        abufh[(size_t)(b * 3 + si) * 256 + head * 64 + d] = (_Float16)o;
    }
}

// ---------------------------------------------------------------------------
// Head: temporal attention + fc1/relu + fc2/relu + fc3. One block per b.
// ---------------------------------------------------------------------------
__global__ __launch_bounds__(256) void head_kernel(
    const float* __restrict__ X, const float* __restrict__ taw, const float* __restrict__ tab,
    const float* __restrict__ f1w, const float* __restrict__ f1b,
    const float* __restrict__ f2w, const float* __restrict__ f2b,
    const float* __restrict__ f3w, const float* __restrict__ f3b,
    float* __restrict__ out)
{
    __shared__ float xs[3 * 256];
    __shared__ float wsm[3];
    __shared__ float cs[256];
    __shared__ float a1[128];
    __shared__ float a2[64];
    int b = blockIdx.x, tid = threadIdx.x;
    for (int idx = tid; idx < 768; idx += 256) xs[idx] = X[(size_t)b * 768 + idx];
    __syncthreads();
    if (tid < 3) {
        float s = tab[0];
        for (int d = 0; d < 256; ++d) s = fmaf(xs[tid * 256 + d], taw[d], s);
        wsm[tid] = s;
    }
    __syncthreads();
    {
        float m = fmaxf(wsm[0], fmaxf(wsm[1], wsm[2]));
        float e0 = expf(wsm[0] - m), e1 = expf(wsm[1] - m), e2 = expf(wsm[2] - m);
        float den = e0 + e1 + e2;
        cs[tid] = (e0 * xs[tid] + e1 * xs[256 + tid] + e2 * xs[512 + tid]) / den;
    }
    __syncthreads();
    if (tid < 128) {
        float a = f1b[tid];
        const float* w = f1w + tid * 256;
        for (int c = 0; c < 256; ++c) a = fmaf(cs[c], w[c], a);
        a1[tid] = fmaxf(a, 0.f);
    }
    __syncthreads();
    if (tid < 64) {
        float a = f2b[tid];
        const float* w = f2w + tid * 128;
        for (int c = 0; c < 128; ++c) a = fmaf(a1[c], w[c], a);
        a2[tid] = fmaxf(a, 0.f);
    }
    __syncthreads();
    if (tid < 5) {
        float a = f3b[tid];
        const float* w = f3w + tid * 64;
        for (int c = 0; c < 64; ++c) a = fmaf(a2[c], w[c], a);
        out[b * 5 + tid] = a;
    }
}

// ---------------------------------------------------------------------------
extern "C" void kernel_launch(void* const* d_in, const int* in_sizes, int n_in,
                              void* d_out, int out_size, void* d_ws, size_t ws_size,
                              hipStream_t stream) {
    const float* x_t     = (const float*)d_in[0];
    const float* x_f     = (const float*)d_in[1];
    const float* conv1_w = (const float*)d_in[2];
    const float* conv1_b = (const float*)d_in[3];
    const float* bn1_g   = (const float*)d_in[4];
    const float* bn1_b   = (const float*)d_in[5];
    const float* bn1_m   = (const float*)d_in[6];
    const float* bn1_v   = (const float*)d_in[7];
    const float* conv2_w = (const float*)d_in[8];
    const float* conv2_b = (const float*)d_in[9];
    const float* bn2_g   = (const float*)d_in[10];
    const float* bn2_b   = (const float*)d_in[11];
    const float* bn2_m   = (const float*)d_in[12];
    const float* bn2_v   = (const float*)d_in[13];
    const float* conv3_w = (const float*)d_in[14];
    const float* conv3_b = (const float*)d_in[15];
    const float* bn3_g   = (const float*)d_in[16];
    const float* bn3_b   = (const float*)d_in[17];
    const float* bn3_m   = (const float*)d_in[18];
    const float* bn3_v   = (const float*)d_in[19];
    const float* gat_lin_w   = (const float*)d_in[20];
    const float* gat_att_src = (const float*)d_in[21];
    const float* gat_att_dst = (const float*)d_in[22];
    const float* gat_bias    = (const float*)d_in[23];
    const float* feat_proj_w = (const float*)d_in[24];
    const float* feat_proj_b = (const float*)d_in[25];
    const float* tr_in_w  = (const float*)d_in[26];
    const float* tr_in_b  = (const float*)d_in[27];
    const float* tr_out_w = (const float*)d_in[28];
    const float* tr_out_b = (const float*)d_in[29];
    const float* tr_l1_w  = (const float*)d_in[30];
    const float* tr_l1_b  = (const float*)d_in[31];
    const float* tr_l2_w  = (const float*)d_in[32];
    const float* tr_l2_b  = (const float*)d_in[33];
    const float* tr_ln1_g = (const float*)d_in[34];
    const float* tr_ln1_b = (const float*)d_in[35];
    const float* tr_ln2_g = (const float*)d_in[36];
    const float* tr_ln2_b = (const float*)d_in[37];
    const float* ta_w  = (const float*)d_in[38];
    const float* ta_b  = (const float*)d_in[39];
    const float* fc1_w = (const float*)d_in[40];
    const float* fc1_b = (const float*)d_in[41];
    const float* fc2_w = (const float*)d_in[42];
    const float* fc2_b = (const float*)d_in[43];
    const float* fc3_w = (const float*)d_in[44];
    const float* fc3_b = (const float*)d_in[45];

    float* ws    = (float*)d_ws;
    float* POOL  = ws + WS_POOL;
    float* X     = ws + WS_X;
    float* QKV   = ws + WS_SCR;                    // f32 [768][768]
    _Float16* GOUTH = (_Float16*)(ws + WS_SCR);    // f16 [768][1024]
    _Float16* MIDH  = (_Float16*)(ws + WS_SCR);    // f16 [768][1024]
    _Float16* XH    = (_Float16*)(ws + WS_XH);
    _Float16* ABH   = (_Float16*)(ws + WS_ABH);
    const _Float16* FPWH  = (const _Float16*)(ws + WS_FPWH);
    const _Float16* INWH  = (const _Float16*)(ws + WS_INWH);
    const _Float16* OUTWH = (const _Float16*)(ws + WS_OUTWH);
    const _Float16* L1WH  = (const _Float16*)(ws + WS_L1WH);
    const _Float16* L2WH  = (const _Float16*)(ws + WS_L2WH);
    float* out = (float*)d_out;

    prep_kernel<<<192, 256, 0, stream>>>(conv1_w, conv2_w, conv3_w,
        conv1_b, bn1_g, bn1_b, bn1_m, bn1_v,
        conv2_b, bn2_g, bn2_b, bn2_m, bn2_v,
        conv3_b, bn3_g, bn3_b, bn3_m, bn3_v, ws);
    prep_tr_kernel<<<2048, 256, 0, stream>>>(feat_proj_w, tr_in_w, tr_out_w,
                                             tr_l1_w, tr_l2_w, ws);

    conv_mfma_kernel<<<dim3(Gn, 2), 256, 0, stream>>>(x_t, x_f, ws, POOL);

    gat_kernel<<<Gn, 256, 0, stream>>>(gat_lin_w, gat_att_src, gat_att_dst, gat_bias,
                                       POOL, GOUTH);

    // feat_proj + PE: X = GOUTH @ fpw^T + fpb + pe   (M=768, K=1024, N=256)
    mfma_gemm_kernel<1024, 3><<<dim3(12, 4), 256, 0, stream>>>(
        GOUTH, FPWH, feat_proj_b, X, XH, 256);

    for (int l = 0; l < TLn; ++l) {
        mfma_gemm_kernel<256, 0><<<dim3(12, 12), 256, 0, stream>>>(
            XH, INWH + (size_t)l * 196608, tr_in_b + l * 768, QKV, nullptr, 768);
        attn_kernel<<<Bn, 256, 0, stream>>>(QKV, ABH);
        gemm_ln_kernel<256><<<48, 256, 0, stream>>>(
            ABH, OUTWH + (size_t)l * 65536, tr_out_b + l * 256,
            tr_ln1_g + l * 256, tr_ln1_b + l * 256, X, XH);
        mfma_gemm_kernel<256, 1><<<dim3(12, 16), 256, 0, stream>>>(
            XH, L1WH + (size_t)l * 262144, tr_l1_b + l * 1024, nullptr, MIDH, 1024);
        gemm_ln_kernel<1024><<<48, 256, 0, stream>>>(
            MIDH, L2WH + (size_t)l * 262144, tr_l2_b + l * 256,
            tr_ln2_g + l * 256, tr_ln2_b + l * 256, X, XH);
    }

    head_kernel<<<Bn, 256, 0, stream>>>(X, ta_w, ta_b, fc1_w, fc1_b,
                                        fc2_w, fc2_b, fc3_w, fc3_b, out);
}

// Round 7
// 764.816 us; speedup vs baseline: 1.1545x; 1.0158x over previous
//
#include <hip/hip_runtime.h>
#include <math.h>

// ---------------------------------------------------------------------------
// Sizes
// ---------------------------------------------------------------------------
#define Bn 256
#define Sn 3
#define Ln 4096
#define Gn 768          // B*S
#define TDn 256
#define TLn 2

// Workspace layout (float offsets)
#define WS_W1K   0        // 1024 fl  (2048 f16)   [br][oc32][k32]
#define WS_W2K   1024     // 14336 fl (28672 f16)  [br][oc64][k224]
#define WS_W3K   15360    // 24576 fl (49152 f16)  [br][oc128][k192]
#define WS_H1    39936    // 64
#define WS_H2    40000    // 128
#define WS_H3    40128    // 256
#define WS_FPWH  40960    // 131072 fl = 262144 f16  fpw [256][1024]
#define WS_INWH  172032   // 196608 fl = 393216 f16  [TL][768][256]
#define WS_OUTWH 368640   // 65536 fl  = 131072 f16  [TL][256][256]
#define WS_L1WH  434176   // 262144 fl = 524288 f16  [TL][1024][256]
#define WS_L2WH  696320   // 262144 fl = 524288 f16  [TL][256][1024]
#define WS_POOL  958464   // 196608 fl f32 [768][256]  (dead after gat ->)
#define WS_XH    958464   //   98304 fl = 196608 f16 [768][256]
#define WS_ABH   1056768  //   98304 fl = 196608 f16 [768][256]
#define WS_SCR   1155072  // 589824 fl: GOUTH f16[768][1024] | QKV f32[768][768] | MIDH f16[768][1024]
#define WS_Y     1548288  // 196608 fl (unused)
#define WS_X     1744896  // 196608 fl f32 [768][256]
// end: 1941504 floats = 7.77 MB

typedef _Float16 f16x8 __attribute__((ext_vector_type(8)));
typedef float f32x4 __attribute__((ext_vector_type(4)));
#define MFMA16(a,b,c) __builtin_amdgcn_mfma_f32_16x16x32_f16(a,b,c,0,0,0)

// ---------------------------------------------------------------------------
// K0a: conv weight transpose to f16 + BN fold
// ---------------------------------------------------------------------------
__global__ __launch_bounds__(256) void prep_kernel(
    const float* __restrict__ w1, const float* __restrict__ w2, const float* __restrict__ w3,
    const float* __restrict__ c1b, const float* __restrict__ g1, const float* __restrict__ b1,
    const float* __restrict__ m1, const float* __restrict__ v1,
    const float* __restrict__ c2b, const float* __restrict__ g2, const float* __restrict__ b2,
    const float* __restrict__ m2, const float* __restrict__ v2,
    const float* __restrict__ c3b, const float* __restrict__ g3, const float* __restrict__ b3,
    const float* __restrict__ m3, const float* __restrict__ v3,
    float* __restrict__ ws)
{
    int i = blockIdx.x * 256 + threadIdx.x;
    _Float16* w1k = (_Float16*)(ws + WS_W1K);
    _Float16* w2k = (_Float16*)(ws + WS_W2K);
    _Float16* w3k = (_Float16*)(ws + WS_W3K);
    if (i < 2048) { // i = (br*32+oc)*32 + c*16+tau
        int k = i & 31, oc = (i >> 5) & 31, br = i >> 10;
        int c = k >> 4, tau = k & 15;
        int a = br * 32 + oc;
        float s = g1[a] / sqrtf(v1[a] + 1e-5f);
        float v = (tau < 15) ? w1[(((size_t)a * 2 + c) * 15) + tau] * s : 0.f;
        w1k[i] = (_Float16)v;
    }
    if (i < 28672) { // i = (br*64+oc)*224 + tblk*32+ic
        int k = i % 224; int a = i / 224;
        int tblk = k >> 5, ic = k & 31;
        int t = (tblk < 4) ? 2 * tblk : 2 * (tblk - 4) + 1;
        float s = g2[a] / sqrtf(v2[a] + 1e-5f);
        w2k[i] = (_Float16)(w2[((size_t)a * 32 + ic) * 7 + t] * s);
    }
    if (i < 49152) { // i = (br*128+oc)*192 + t*64+ic
        int k = i % 192; int a = i / 192;
        int t = k >> 6, ic = k & 63;
        float s = g3[a] / sqrtf(v3[a] + 1e-5f);
        w3k[i] = (_Float16)(w3[((size_t)a * 64 + ic) * 3 + t] * s);
    }
    if (i < 64)  { float s = g1[i] / sqrtf(v1[i] + 1e-5f); ws[WS_H1 + i] = (c1b[i] - m1[i]) * s + b1[i]; }
    if (i < 128) { float s = g2[i] / sqrtf(v2[i] + 1e-5f); ws[WS_H2 + i] = (c2b[i] - m2[i]) * s + b2[i]; }
    if (i < 256) { float s = g3[i] / sqrtf(v3[i] + 1e-5f); ws[WS_H3 + i] = (c3b[i] - m3[i]) * s + b3[i]; }
}

// ---------------------------------------------------------------------------
// K0b: transformer / feat_proj weights -> f16 (layouts already [N][K])
// ---------------------------------------------------------------------------
__global__ __launch_bounds__(256) void prep_tr_kernel(
    const float* __restrict__ fpw, const float* __restrict__ inw,
    const float* __restrict__ outw, const float* __restrict__ l1w,
    const float* __restrict__ l2w, float* __restrict__ ws)
{
    int i = blockIdx.x * 256 + threadIdx.x;
    _Float16* fpwh = (_Float16*)(ws + WS_FPWH);
    _Float16* inwh = (_Float16*)(ws + WS_INWH);
    _Float16* outwh = (_Float16*)(ws + WS_OUTWH);
    _Float16* l1wh = (_Float16*)(ws + WS_L1WH);
    _Float16* l2wh = (_Float16*)(ws + WS_L2WH);
    if (i < 262144) fpwh[i] = (_Float16)fpw[i];
    if (i < 393216) inwh[i] = (_Float16)inw[i];
    if (i < 131072) outwh[i] = (_Float16)outw[i];
    if (i < 524288) { l1wh[i] = (_Float16)l1w[i]; l2wh[i] = (_Float16)l2w[i]; }
}

// ---------------------------------------------------------------------------
// K1: fused conv1->conv2->conv3->mean-pool via fp16 MFMA.
// Round-7:
//  - (256,3): 170-reg budget; split conv2 passes + prefetch fit (~130 live)
//  - 1-deep weight prefetch restored in conv2 AND conv3 (round-4/6 A/B showed
//    prefetch > occupancy: 449@2blk vs 491@3blk)
//  - barriers 36 -> 19: xsf/y1/y2s are disjoint, so conv3(t)|conv1(t+1) can
//    overlap; only conv1->conv2 and conv2->conv3 need syncs
//  - x staging software-pipelined through registers (HBM latency hides
//    behind conv2's MFMAs; xsf overwrite safe after B2 = conv1 reads done)
// ---------------------------------------------------------------------------
__global__ __launch_bounds__(256, 3) void conv_mfma_kernel(
    const float* __restrict__ x_t, const float* __restrict__ x_f,
    const float* __restrict__ ws, float* __restrict__ pooled)
{
    __shared__ _Float16 xsf[2 * 576];       // [c][l], f16
    __shared__ _Float16 y1[2][132 * 32];    // [parity][row i][ic granule-swizzled]
    __shared__ _Float16 y2s[128 * 64];      // [row n][oc granule-swizzled]
    __shared__ float h1s[32];
    __shared__ float h2s[64];
    __shared__ float h3s[128];
    __shared__ float pbuf[128];

    const int g = blockIdx.x, br = blockIdx.y;
    const int tid = threadIdx.x;
    const int lane = tid & 63, wv = tid >> 6;
    const int l15 = lane & 15, q4 = lane >> 4;

    const float* xin = (br == 0 ? x_t : x_f) + (size_t)g * (Ln * 2);
    const _Float16* w1k = (const _Float16*)(ws + WS_W1K) + br * 1024;
    const _Float16* w2k = (const _Float16*)(ws + WS_W2K) + br * 14336;
    const _Float16* w3k = (const _Float16*)(ws + WS_W3K) + br * 24576;

    if (tid < 32)  h1s[tid] = ws[WS_H1 + br * 32 + tid];
    if (tid < 64)  h2s[tid] = ws[WS_H2 + br * 64 + tid];
    if (tid < 128) { h3s[tid] = ws[WS_H3 + br * 128 + tid]; pbuf[tid] = 0.f; }

    // conv1 A-frags (weights, resident, 8 VGPRs): A[m=l15][k=q4*8+j]
    f16x8 a1[2];
    #pragma unroll
    for (int mt = 0; mt < 2; ++mt)
        a1[mt] = *(const f16x8*)(w1k + (mt * 16 + l15) * 32 + q4 * 8);

    const int mg = wv & 1, ng = wv >> 1;

    // per-wave weight row bases
    const _Float16* w2row = w2k + (size_t)l15 * 224 + q4 * 8;
    const _Float16* w3row = w3k + (size_t)(mg * 64 + l15) * 192 + q4 * 8;

    float pool_[4][4];
    #pragma unroll
    for (int mt = 0; mt < 4; ++mt)
        #pragma unroll
        for (int r = 0; r < 4; ++r) pool_[mt][r] = 0.f;

    const f32x4 vzero = {0.f, 0.f, 0.f, 0.f};

    // ---- prologue: stage tile 0 -> xsf ----
    for (int l = tid; l < 576; l += 256) {
        int xl = -17 + l;
        float a = 0.f, b = 0.f;
        if (xl >= 0 && xl < Ln) { float2 v = *(const float2*)(xin + (size_t)xl * 2); a = v.x; b = v.y; }
        xsf[l] = (_Float16)a; xsf[576 + l] = (_Float16)b;
    }
    __syncthreads();

    #pragma unroll 1
    for (int tile = 0; tile < 9; ++tile) {
        const int P0 = tile * 126;
        const int Q0 = 2 * P0 - 5;

        // ---- conv1 MFMA: M=32 (2 tiles), N=261 (17 tiles), K=32 ----
        const uint* xsu = (const uint*)xsf;
        #pragma unroll 1
        for (int nt = wv; nt < 17; nt += 4) {
            int j0 = nt * 16 + l15;
            union { f16x8 v; uint u[4]; } bf;
            int ubase = (q4 >> 1) * 288 + j0 + (q4 & 1) * 4;
            #pragma unroll
            for (int ii = 0; ii < 4; ++ii) bf.u[ii] = xsu[ubase + ii];
            f32x4 c1acc[2] = {vzero, vzero};
            c1acc[0] = MFMA16(a1[0], bf.v, c1acc[0]);
            c1acc[1] = MFMA16(a1[1], bf.v, c1acc[1]);

            if (j0 <= 260) {
                int q = Q0 + j0;
                bool val = (q >= 0) && (q < 2048);
                int i = j0 >> 1, par = j0 & 1;
                #pragma unroll
                for (int mt = 0; mt < 2; ++mt) {
                    int oc0 = mt * 16 + q4 * 4;
                    union { _Float16 h[4]; uint2 u; } pk;
                    #pragma unroll
                    for (int r = 0; r < 4; ++r) {
                        float y = c1acc[mt][r] + h1s[oc0 + r];
                        y = y > 0.f ? y : 0.f;
                        pk.h[r] = val ? (_Float16)y : (_Float16)0.f;
                    }
                    int gq = mt * 2 + (q4 >> 1), sub = q4 & 1;
                    *(uint2*)(&y1[par][(i * 4 + (gq ^ (i & 3))) * 8 + sub * 4]) = pk.u;
                }
            }
        }
        __syncthreads();   // B2: y1 ready; conv1's xsf reads done

        // ---- issue next tile's x loads (HBM latency overlaps conv2) ----
        float2 xr0 = {0.f, 0.f}, xr1 = {0.f, 0.f}, xr2 = {0.f, 0.f};
        if (tile < 8) {
            const int xn0 = 4 * (P0 + 126) - 17;
            { int xl = xn0 + tid;       if (xl < Ln) xr0 = *(const float2*)(xin + (size_t)xl * 2); }
            { int xl = xn0 + tid + 256; if (xl < Ln) xr1 = *(const float2*)(xin + (size_t)xl * 2); }
            if (tid < 64) { int xl = xn0 + tid + 512; if (xl < Ln) xr2 = *(const float2*)(xin + (size_t)xl * 2); }
        }

        // ---- conv2 MFMA: M=64 (4 tiles), N=128, K=224; two jj passes,
        //      1-deep weight prefetch ----
        #pragma unroll 1
        for (int jj = 0; jj < 2; ++jj) {
            f32x4 c2[4] = {vzero, vzero, vzero, vzero};
            f16x8 a2c[4];
            #pragma unroll
            for (int mt = 0; mt < 4; ++mt)
                a2c[mt] = *(const f16x8*)(w2row + (size_t)mt * 16 * 224);
            const int n = wv * 32 + jj * 16 + l15;
            #pragma unroll 1
            for (int ks = 0; ks < 7; ++ks) {
                int roff = (ks < 4) ? ks : ks - 4;
                const _Float16* yb = y1[(ks < 4) ? 0 : 1];
                int i = n + roff;
                f16x8 bb = *(const f16x8*)(yb + (i * 4 + (q4 ^ (i & 3))) * 8);
                f16x8 a2n[4];
                if (ks < 6) {
                    #pragma unroll
                    for (int mt = 0; mt < 4; ++mt)
                        a2n[mt] = *(const f16x8*)(w2row + (size_t)mt * 16 * 224 + (ks + 1) * 32);
                }
                #pragma unroll
                for (int mt = 0; mt < 4; ++mt)
                    c2[mt] = MFMA16(a2c[mt], bb, c2[mt]);
                if (ks < 6) {
                    #pragma unroll
                    for (int mt = 0; mt < 4; ++mt) a2c[mt] = a2n[mt];
                }
            }
            int p2 = P0 - 1 + n;
            bool val = (p2 >= 0) && (p2 < 1024);
            #pragma unroll
            for (int mt = 0; mt < 4; ++mt) {
                int oc0 = mt * 16 + q4 * 4;
                union { _Float16 h[4]; uint2 u; } pk;
                #pragma unroll
                for (int r = 0; r < 4; ++r) {
                    float y = c2[mt][r] + h2s[oc0 + r];
                    y = y > 0.f ? y : 0.f;
                    pk.h[r] = val ? (_Float16)y : (_Float16)0.f;
                }
                int gq = oc0 >> 3, sub = q4 & 1;
                *(uint2*)(&y2s[(n * 8 + (gq ^ (n & 7))) * 8 + sub * 4]) = pk.u;
            }
        }

        // ---- write staged x -> xsf (safe: conv1 reads finished at B2) ----
        if (tile < 8) {
            { int l = tid;       xsf[l] = (_Float16)xr0.x; xsf[576 + l] = (_Float16)xr0.y; }
            { int l = tid + 256; xsf[l] = (_Float16)xr1.x; xsf[576 + l] = (_Float16)xr1.y; }
            if (tid < 64) { int l = tid + 512; xsf[l] = (_Float16)xr2.x; xsf[576 + l] = (_Float16)xr2.y; }
        }
        __syncthreads();   // B3: y2s + staged xsf ready

        // ---- conv3 MFMA + pool: M=128, N=126(128), K=192; two N-halves,
        //      1-deep weight prefetch ----
        #pragma unroll 1
        for (int half = 0; half < 2; ++half) {
            f32x4 c3[4][2];
            #pragma unroll
            for (int mt = 0; mt < 4; ++mt) { c3[mt][0] = vzero; c3[mt][1] = vzero; }
            f16x8 a3c[4];
            #pragma unroll
            for (int mt = 0; mt < 4; ++mt)
                a3c[mt] = *(const f16x8*)(w3row + (size_t)mt * 16 * 192);
            #pragma unroll 1
            for (int ks = 0; ks < 6; ++ks) {
                int t = ks >> 1, ich = ks & 1;
                f16x8 b3[2];
                #pragma unroll
                for (int jj = 0; jj < 2; ++jj) {
                    int np = ng * 64 + (half * 2 + jj) * 16 + l15;
                    int r = np + t; r = r < 128 ? r : 127;   // clamp (masked later)
                    int gq3 = ich * 4 + q4;
                    b3[jj] = *(const f16x8*)(&y2s[(r * 8 + (gq3 ^ (r & 7))) * 8]);
                }
                f16x8 a3n[4];
                if (ks < 5) {
                    #pragma unroll
                    for (int mt = 0; mt < 4; ++mt)
                        a3n[mt] = *(const f16x8*)(w3row + (size_t)mt * 16 * 192 + (ks + 1) * 32);
                }
                #pragma unroll
                for (int mt = 0; mt < 4; ++mt) {
                    c3[mt][0] = MFMA16(a3c[mt], b3[0], c3[mt][0]);
                    c3[mt][1] = MFMA16(a3c[mt], b3[1], c3[mt][1]);
                }
                if (ks < 5) {
                    #pragma unroll
                    for (int mt = 0; mt < 4; ++mt) a3c[mt] = a3n[mt];
                }
            }
            #pragma unroll
            for (int mt = 0; mt < 4; ++mt) {
                int oc0 = mg * 64 + mt * 16 + q4 * 4;
                #pragma unroll
                for (int jj = 0; jj < 2; ++jj) {
                    int np = ng * 64 + (half * 2 + jj) * 16 + l15;
                    int p3 = P0 + np;
                    float valf = ((np < 126) && (p3 < 1024)) ? 1.f : 0.f;
                    #pragma unroll
                    for (int r = 0; r < 4; ++r) {
                        float y = c3[mt][jj][r] + h3s[oc0 + r];
                        y = y > 0.f ? y : 0.f;
                        pool_[mt][r] = fmaf(y, valf, pool_[mt][r]);
                    }
                }
            }
        }
        // no loop-end barrier: conv1(t+1) touches xsf/y1 only, disjoint from
        // conv3's y2s reads; y2s WAR protected by B2(t+1)
    }

    // ---- pool: reduce over 16 n-lanes, combine waves via LDS, plain store ----
    #pragma unroll
    for (int mt = 0; mt < 4; ++mt)
        #pragma unroll
        for (int r = 0; r < 4; ++r) {
            float v = pool_[mt][r];
            v += __shfl_xor(v, 1, 64);
            v += __shfl_xor(v, 2, 64);
            v += __shfl_xor(v, 4, 64);
            v += __shfl_xor(v, 8, 64);
            if (l15 == 0) atomicAdd(&pbuf[mg * 64 + mt * 16 + q4 * 4 + r], v);
        }
    __syncthreads();
    if (tid < 128) pooled[g * 256 + br * 128 + tid] = pbuf[tid] * (1.f / 1024.f);
}

// ---------------------------------------------------------------------------
// K2: GAT -> f16 gat_out [g][1024]. One block per g.
// ---------------------------------------------------------------------------
__global__ __launch_bounds__(256) void gat_kernel(
    const float* __restrict__ glw, const float* __restrict__ att_src,
    const float* __restrict__ att_dst, const float* __restrict__ gbias,
    const float* __restrict__ pooled, _Float16* __restrict__ gouth)
{
    __shared__ float feats[256];
    __shared__ float hs[4 * 256];
    __shared__ float av[32];
    __shared__ float alpha[64];

    int g = blockIdx.x, tid = threadIdx.x;
    feats[tid] = pooled[g * 256 + tid];
    __syncthreads();

    { // h[n,o] = sum_c feat[n,c] * W[o,c]
        int o = tid;
        const float* w = glw + o * 64;
        float a0 = 0, a1 = 0, a2 = 0, a3 = 0;
        for (int c = 0; c < 64; ++c) {
            float wvv = w[c];
            a0 = fmaf(feats[c],       wvv, a0);
            a1 = fmaf(feats[64 + c],  wvv, a1);
            a2 = fmaf(feats[128 + c], wvv, a2);
            a3 = fmaf(feats[192 + c], wvv, a3);
        }
        hs[o] = a0; hs[256 + o] = a1; hs[512 + o] = a2; hs[768 + o] = a3;
    }
    __syncthreads();

    if (tid < 32) {
        int n = (tid & 15) >> 2, hd = tid & 3;
        const float* aw = (tid < 16) ? att_src : att_dst;
        float s = 0;
        for (int d = 0; d < 64; ++d) s = fmaf(hs[n * 256 + hd * 64 + d], aw[hd * 64 + d], s);
        av[tid] = s;
    }
    __syncthreads();

    if (tid < 16) {
        int i = tid >> 2, hd = tid & 3;
        float sc[4], mx = -1e30f;
        #pragma unroll
        for (int j = 0; j < 4; ++j) {
            float v = av[16 + i * 4 + hd] + av[j * 4 + hd];
            v = v > 0.f ? v : 0.2f * v;
            sc[j] = v; mx = fmaxf(mx, v);
        }
        float den = 0;
        #pragma unroll
        for (int j = 0; j < 4; ++j) { sc[j] = expf(sc[j] - mx); den += sc[j]; }
        #pragma unroll
        for (int j = 0; j < 4; ++j) alpha[(i * 4 + j) * 4 + hd] = sc[j] / den;
    }
    __syncthreads();

    { // gat_out[i,o] -> f16 global
        int o = tid, hd = o >> 6;
        #pragma unroll
        for (int i = 0; i < 4; ++i) {
            float acc = gbias[o];
            #pragma unroll
            for (int j = 0; j < 4; ++j) acc = fmaf(alpha[(i * 4 + j) * 4 + hd], hs[j * 256 + o], acc);
            gouth[(size_t)g * 1024 + i * 256 + o] = (_Float16)acc;
        }
    }
}

// ---------------------------------------------------------------------------
// MFMA GEMM: C[m][n] = A[m][K] . W[n][K] + bias.  Block tile 64x64, wave 16x64.
// MODE 0: f32 out.  MODE 1: relu -> f16 out.  MODE 3: +PE -> f32 + f16.
// ---------------------------------------------------------------------------
template <int K, int MODE>
__global__ __launch_bounds__(256) void mfma_gemm_kernel(
    const _Float16* __restrict__ A, const _Float16* __restrict__ W,
    const float* __restrict__ bias, float* __restrict__ out32,
    _Float16* __restrict__ out16, int N)
{
    const int tid = threadIdx.x;
    const int wv = tid >> 6, l15 = tid & 15, q4 = (tid & 63) >> 4;
    const int m0 = blockIdx.x * 64 + wv * 16;
    const int n0 = blockIdx.y * 64;

    const f32x4 vzero = {0.f, 0.f, 0.f, 0.f};
    f32x4 acc[4] = {vzero, vzero, vzero, vzero};

    const _Float16* arow = A + (size_t)(m0 + l15) * K + q4 * 8;
    #pragma unroll 4
    for (int ks = 0; ks < K / 32; ++ks) {
        f16x8 a = *(const f16x8*)(arow + ks * 32);
        #pragma unroll
        for (int nt = 0; nt < 4; ++nt) {
            f16x8 b = *(const f16x8*)(W + (size_t)(n0 + nt * 16 + l15) * K + ks * 32 + q4 * 8);
            acc[nt] = MFMA16(a, b, acc[nt]);
        }
    }

    #pragma unroll
    for (int nt = 0; nt < 4; ++nt) {
        int n = n0 + nt * 16 + l15;
        float bs = bias[n];
        #pragma unroll
        for (int r = 0; r < 4; ++r) {
            int m = m0 + q4 * 4 + r;
            float v = acc[nt][r] + bs;
            if (MODE == 1) v = fmaxf(v, 0.f);
            if (MODE == 3) {
                int s = m % 3;
                int kk = n >> 1;
                float dv = expf((float)kk * -0.07195588f);  // -2*ln(1e4)/256
                float arg = (float)s * dv;
                v += (n & 1) ? cosf(arg) : sinf(arg);
            }
            if (MODE == 0 || MODE == 3) out32[(size_t)m * N + n] = v;
            if (MODE == 1 || MODE == 3) out16[(size_t)m * N + n] = (_Float16)v;
        }
    }
}

// ---------------------------------------------------------------------------
// Fused MFMA GEMM (N=256) + bias + residual + LayerNorm.
// Block = 16 rows x 256 cols; wave tile 16x64. Grid = 48 blocks.
// ---------------------------------------------------------------------------
template <int K>
__global__ __launch_bounds__(256) void gemm_ln_kernel(
    const _Float16* __restrict__ A, const _Float16* __restrict__ W,
    const float* __restrict__ bias,
    const float* __restrict__ gamma, const float* __restrict__ beta,
    float* __restrict__ X, _Float16* __restrict__ XH)
{
    __shared__ float ys[16][260];
    const int tid = threadIdx.x;
    const int wv = tid >> 6, l15 = tid & 15, q4 = (tid & 63) >> 4;
    const int r0 = blockIdx.x * 16;
    const int n0 = wv * 64;

    const f32x4 vzero = {0.f, 0.f, 0.f, 0.f};
    f32x4 acc[4] = {vzero, vzero, vzero, vzero};

    const _Float16* arow = A + (size_t)(r0 + l15) * K + q4 * 8;
    #pragma unroll 4
    for (int ks = 0; ks < K / 32; ++ks) {
        f16x8 a = *(const f16x8*)(arow + ks * 32);
        #pragma unroll
        for (int nt = 0; nt < 4; ++nt) {
            f16x8 b = *(const f16x8*)(W + (size_t)(n0 + nt * 16 + l15) * K + ks * 32 + q4 * 8);
            acc[nt] = MFMA16(a, b, acc[nt]);
        }
    }

    #pragma unroll
    for (int nt = 0; nt < 4; ++nt) {
        int col = n0 + nt * 16 + l15;
        float bs = bias[col];
        #pragma unroll
        for (int r = 0; r < 4; ++r) {
            int rowl = q4 * 4 + r;
            ys[rowl][col] = acc[nt][r] + bs + X[(size_t)(r0 + rowl) * 256 + col];
        }
    }
    __syncthreads();

    {
        int row = tid >> 4, l16 = tid & 15;
        float s = 0, s2 = 0;
        #pragma unroll
        for (int c0 = 0; c0 < 256; c0 += 16) {
            float v = ys[row][c0 + l16]; s += v; s2 += v * v;
        }
        s += __shfl_xor(s, 1, 64);  s2 += __shfl_xor(s2, 1, 64);
        s += __shfl_xor(s, 2, 64);  s2 += __shfl_xor(s2, 2, 64);
        s += __shfl_xor(s, 4, 64);  s2 += __shfl_xor(s2, 4, 64);
        s += __shfl_xor(s, 8, 64);  s2 += __shfl_xor(s2, 8, 64);
        float mu = s * (1.f / 256.f);
        float var = s2 * (1.f / 256.f) - mu * mu;
        float inv = 1.0f / sqrtf(var + 1e-5f);
        #pragma unroll
        for (int c0 = 0; c0 < 256; c0 += 16) {
            int c = c0 + l16;
            float v = (ys[row][c] - mu) * inv * gamma[c] + beta[c];
            X[(size_t)(r0 + row) * 256 + c] = v;
            XH[(size_t)(r0 + row) * 256 + c] = (_Float16)v;
        }
    }
}

// ---------------------------------------------------------------------------
// Attention: S=3, one block per batch b, one wave per head. f32 in, f16 out.
// ---------------------------------------------------------------------------
__global__ __launch_bounds__(256) void attn_kernel(
    const float* __restrict__ qkv, _Float16* __restrict__ abufh)
{
    int b = blockIdx.x, tid = threadIdx.x, head = tid >> 6, d = tid & 63;
    const float* base = qkv + (size_t)b * 3 * 768 + head * 64 + d;
    float q[3], k[3], v[3];
    #pragma unroll
    for (int s = 0; s < 3; ++s) {
        const float* row = base + s * 768;
        q[s] = row[0]; k[s] = row[256]; v[s] = row[512];
    }
    float sc[3][3];
    #pragma unroll
    for (int si = 0; si < 3; ++si)
        #pragma unroll
        for (int sj = 0; sj < 3; ++sj) {
            float p = q[si] * k[sj];
            #pragma unroll
            for (int m = 32; m > 0; m >>= 1) p += __shfl_xor(p, m, 64);
            sc[si][sj] = p * 0.125f;
        }
    #pragma unroll
    for (int si = 0; si < 3; ++si) {
        float mx = fmaxf(sc[si][0], fmaxf(sc[si][1], sc[si][2]));
        float e0 = expf(sc[si][0] - mx), e1 = expf(sc[si][1] - mx), e2 = expf(sc[si][2] - mx);
        float den = e0 + e1 + e2;
        float o = (e0 * v[0] + e1 * v[1] + e2 * v[2]) / den;
        abufh[(size_t)(b * 3 + si) * 256 + head * 64 + d] = (_Float16)o;
    }
}

// ---------------------------------------------------------------------------
// Head: temporal attention + fc1/relu + fc2/relu + fc3. One block per b.
// ---------------------------------------------------------------------------
__global__ __launch_bounds__(256) void head_kernel(
    const float* __restrict__ X, const float* __restrict__ taw, const float* __restrict__ tab,
    const float* __restrict__ f1w, const float* __restrict__ f1b,
    const float* __restrict__ f2w, const float* __restrict__ f2b,
    const float* __restrict__ f3w, const float* __restrict__ f3b,
    float* __restrict__ out)
{
    __shared__ float xs[3 * 256];
    __shared__ float wsm[3];
    __shared__ float cs[256];
    __shared__ float a1[128];
    __shared__ float a2[64];
    int b = blockIdx.x, tid = threadIdx.x;
    for (int idx = tid; idx < 768; idx += 256) xs[idx] = X[(size_t)b * 768 + idx];
    __syncthreads();
    if (tid < 3) {
        float s = tab[0];
        for (int d = 0; d < 256; ++d) s = fmaf(xs[tid * 256 + d], taw[d], s);
        wsm[tid] = s;
    }
    __syncthreads();
    {
        float m = fmaxf(wsm[0], fmaxf(wsm[1], wsm[2]));
        float e0 = expf(wsm[0] - m), e1 = expf(wsm[1] - m), e2 = expf(wsm[2] - m);
        float den = e0 + e1 + e2;
        cs[tid] = (e0 * xs[tid] + e1 * xs[256 + tid] + e2 * xs[512 + tid]) / den;
    }
    __syncthreads();
    if (tid < 128) {
        float a = f1b[tid];
        const float* w = f1w + tid * 256;
        for (int c = 0; c < 256; ++c) a = fmaf(cs[c], w[c], a);
        a1[tid] = fmaxf(a, 0.f);
    }
    __syncthreads();
    if (tid < 64) {
        float a = f2b[tid];
        const float* w = f2w + tid * 128;
        for (int c = 0; c < 128; ++c) a = fmaf(a1[c], w[c], a);
        a2[tid] = fmaxf(a, 0.f);
    }
    __syncthreads();
    if (tid < 5) {
        float a = f3b[tid];
        const float* w = f3w + tid * 64;
        for (int c = 0; c < 64; ++c) a = fmaf(a2[c], w[c], a);
        out[b * 5 + tid] = a;
    }
}

// ---------------------------------------------------------------------------
extern "C" void kernel_launch(void* const* d_in, const int* in_sizes, int n_in,
                              void* d_out, int out_size, void* d_ws, size_t ws_size,
                              hipStream_t stream) {
    const float* x_t     = (const float*)d_in[0];
    const float* x_f     = (const float*)d_in[1];
    const float* conv1_w = (const float*)d_in[2];
    const float* conv1_b = (const float*)d_in[3];
    const float* bn1_g   = (const float*)d_in[4];
    const float* bn1_b   = (const float*)d_in[5];
    const float* bn1_m   = (const float*)d_in[6];
    const float* bn1_v   = (const float*)d_in[7];
    const float* conv2_w = (const float*)d_in[8];
    const float* conv2_b = (const float*)d_in[9];
    const float* bn2_g   = (const float*)d_in[10];
    const float* bn2_b   = (const float*)d_in[11];
    const float* bn2_m   = (const float*)d_in[12];
    const float* bn2_v   = (const float*)d_in[13];
    const float* conv3_w = (const float*)d_in[14];
    const float* conv3_b = (const float*)d_in[15];
    const float* bn3_g   = (const float*)d_in[16];
    const float* bn3_b   = (const float*)d_in[17];
    const float* bn3_m   = (const float*)d_in[18];
    const float* bn3_v   = (const float*)d_in[19];
    const float* gat_lin_w   = (const float*)d_in[20];
    const float* gat_att_src = (const float*)d_in[21];
    const float* gat_att_dst = (const float*)d_in[22];
    const float* gat_bias    = (const float*)d_in[23];
    const float* feat_proj_w = (const float*)d_in[24];
    const float* feat_proj_b = (const float*)d_in[25];
    const float* tr_in_w  = (const float*)d_in[26];
    const float* tr_in_b  = (const float*)d_in[27];
    const float* tr_out_w = (const float*)d_in[28];
    const float* tr_out_b = (const float*)d_in[29];
    const float* tr_l1_w  = (const float*)d_in[30];
    const float* tr_l1_b  = (const float*)d_in[31];
    const float* tr_l2_w  = (const float*)d_in[32];
    const float* tr_l2_b  = (const float*)d_in[33];
    const float* tr_ln1_g = (const float*)d_in[34];
    const float* tr_ln1_b = (const float*)d_in[35];
    const float* tr_ln2_g = (const float*)d_in[36];
    const float* tr_ln2_b = (const float*)d_in[37];
    const float* ta_w  = (const float*)d_in[38];
    const float* ta_b  = (const float*)d_in[39];
    const float* fc1_w = (const float*)d_in[40];
    const float* fc1_b = (const float*)d_in[41];
    const float* fc2_w = (const float*)d_in[42];
    const float* fc2_b = (const float*)d_in[43];
    const float* fc3_w = (const float*)d_in[44];
    const float* fc3_b = (const float*)d_in[45];

    float* ws    = (float*)d_ws;
    float* POOL  = ws + WS_POOL;
    float* X     = ws + WS_X;
    float* QKV   = ws + WS_SCR;                    // f32 [768][768]
    _Float16* GOUTH = (_Float16*)(ws + WS_SCR);    // f16 [768][1024]
    _Float16* MIDH  = (_Float16*)(ws + WS_SCR);    // f16 [768][1024]
    _Float16* XH    = (_Float16*)(ws + WS_XH);
    _Float16* ABH   = (_Float16*)(ws + WS_ABH);
    const _Float16* FPWH  = (const _Float16*)(ws + WS_FPWH);
    const _Float16* INWH  = (const _Float16*)(ws + WS_INWH);
    const _Float16* OUTWH = (const _Float16*)(ws + WS_OUTWH);
    const _Float16* L1WH  = (const _Float16*)(ws + WS_L1WH);
    const _Float16* L2WH  = (const _Float16*)(ws + WS_L2WH);
    float* out = (float*)d_out;

    prep_kernel<<<192, 256, 0, stream>>>(conv1_w, conv2_w, conv3_w,
        conv1_b, bn1_g, bn1_b, bn1_m, bn1_v,
        conv2_b, bn2_g, bn2_b, bn2_m, bn2_v,
        conv3_b, bn3_g, bn3_b, bn3_m, bn3_v, ws);
    prep_tr_kernel<<<2048, 256, 0, stream>>>(feat_proj_w, tr_in_w, tr_out_w,
                                             tr_l1_w, tr_l2_w, ws);

    conv_mfma_kernel<<<dim3(Gn, 2), 256, 0, stream>>>(x_t, x_f, ws, POOL);

    gat_kernel<<<Gn, 256, 0, stream>>>(gat_lin_w, gat_att_src, gat_att_dst, gat_bias,
                                       POOL, GOUTH);

    // feat_proj + PE: X = GOUTH @ fpw^T + fpb + pe   (M=768, K=1024, N=256)
    mfma_gemm_kernel<1024, 3><<<dim3(12, 4), 256, 0, stream>>>(
        GOUTH, FPWH, feat_proj_b, X, XH, 256);

    for (int l = 0; l < TLn; ++l) {
        mfma_gemm_kernel<256, 0><<<dim3(12, 12), 256, 0, stream>>>(
            XH, INWH + (size_t)l * 196608, tr_in_b + l * 768, QKV, nullptr, 768);
        attn_kernel<<<Bn, 256, 0, stream>>>(QKV, ABH);
        gemm_ln_kernel<256><<<48, 256, 0, stream>>>(
            ABH, OUTWH + (size_t)l * 65536, tr_out_b + l * 256,
            tr_ln1_g + l * 256, tr_ln1_b + l * 256, X, XH);
        mfma_gemm_kernel<256, 1><<<dim3(12, 16), 256, 0, stream>>>(
            XH, L1WH + (size_t)l * 262144, tr_l1_b + l * 1024, nullptr, MIDH, 1024);
        gemm_ln_kernel<1024><<<48, 256, 0, stream>>>(
            MIDH, L2WH + (size_t)l * 262144, tr_l2_b + l * 256,
            tr_ln2_g + l * 256, tr_ln2_b + l * 256, X, XH);
    }

    head_kernel<<<Bn, 256, 0, stream>>>(X, ta_w, ta_b, fc1_w, fc1_b,
                                        fc2_w, fc2_b, fc3_w, fc3_b, out);
}

// Round 8
// 707.722 us; speedup vs baseline: 1.2476x; 1.0807x over previous
//
#include <hip/hip_runtime.h>
#include <math.h>

// ---------------------------------------------------------------------------
// Sizes
// ---------------------------------------------------------------------------
#define Bn 256
#define Sn 3
#define Ln 4096
#define Gn 768          // B*S
#define TDn 256
#define TLn 2

// Workspace layout (float offsets)
#define WS_W1K   0        // 1024 fl  (2048 f16)   [br][oc32][k32]
#define WS_W2K   1024     // 14336 fl (28672 f16)  [br][oc64][k224]
#define WS_W3K   15360    // 24576 fl (49152 f16)  [br][oc128][k192]
#define WS_H1    39936    // 64
#define WS_H2    40000    // 128
#define WS_H3    40128    // 256
#define WS_FPWH  40960    // 131072 fl = 262144 f16  fpw [256][1024]
#define WS_INWH  172032   // 196608 fl = 393216 f16  [TL][768][256]
#define WS_OUTWH 368640   // 65536 fl  = 131072 f16  [TL][256][256]
#define WS_L1WH  434176   // 262144 fl = 524288 f16  [TL][1024][256]
#define WS_L2WH  696320   // 262144 fl = 524288 f16  [TL][256][1024]
#define WS_POOL  958464   // 196608 fl f32 [768][256]  (dead after gat ->)
#define WS_XH    958464   //   98304 fl = 196608 f16 [768][256]
#define WS_SCR   1155072  // GOUTH f16[768][1024]
#define WS_X     1744896  // 196608 fl f32 [768][256]
// end: 1941504 floats = 7.77 MB

typedef _Float16 f16x8 __attribute__((ext_vector_type(8)));
typedef float f32x4 __attribute__((ext_vector_type(4)));
#define MFMA16(a,b,c) __builtin_amdgcn_mfma_f32_16x16x32_f16(a,b,c,0,0,0)

// ---------------------------------------------------------------------------
// K0a: conv weight transpose to f16 + BN fold
// ---------------------------------------------------------------------------
__global__ __launch_bounds__(256) void prep_kernel(
    const float* __restrict__ w1, const float* __restrict__ w2, const float* __restrict__ w3,
    const float* __restrict__ c1b, const float* __restrict__ g1, const float* __restrict__ b1,
    const float* __restrict__ m1, const float* __restrict__ v1,
    const float* __restrict__ c2b, const float* __restrict__ g2, const float* __restrict__ b2,
    const float* __restrict__ m2, const float* __restrict__ v2,
    const float* __restrict__ c3b, const float* __restrict__ g3, const float* __restrict__ b3,
    const float* __restrict__ m3, const float* __restrict__ v3,
    float* __restrict__ ws)
{
    int i = blockIdx.x * 256 + threadIdx.x;
    _Float16* w1k = (_Float16*)(ws + WS_W1K);
    _Float16* w2k = (_Float16*)(ws + WS_W2K);
    _Float16* w3k = (_Float16*)(ws + WS_W3K);
    if (i < 2048) { // i = (br*32+oc)*32 + c*16+tau
        int k = i & 31, oc = (i >> 5) & 31, br = i >> 10;
        int c = k >> 4, tau = k & 15;
        int a = br * 32 + oc;
        float s = g1[a] / sqrtf(v1[a] + 1e-5f);
        float v = (tau < 15) ? w1[(((size_t)a * 2 + c) * 15) + tau] * s : 0.f;
        w1k[i] = (_Float16)v;
    }
    if (i < 28672) { // i = (br*64+oc)*224 + tblk*32+ic
        int k = i % 224; int a = i / 224;
        int tblk = k >> 5, ic = k & 31;
        int t = (tblk < 4) ? 2 * tblk : 2 * (tblk - 4) + 1;
        float s = g2[a] / sqrtf(v2[a] + 1e-5f);
        w2k[i] = (_Float16)(w2[((size_t)a * 32 + ic) * 7 + t] * s);
    }
    if (i < 49152) { // i = (br*128+oc)*192 + t*64+ic
        int k = i % 192; int a = i / 192;
        int t = k >> 6, ic = k & 63;
        float s = g3[a] / sqrtf(v3[a] + 1e-5f);
        w3k[i] = (_Float16)(w3[((size_t)a * 64 + ic) * 3 + t] * s);
    }
    if (i < 64)  { float s = g1[i] / sqrtf(v1[i] + 1e-5f); ws[WS_H1 + i] = (c1b[i] - m1[i]) * s + b1[i]; }
    if (i < 128) { float s = g2[i] / sqrtf(v2[i] + 1e-5f); ws[WS_H2 + i] = (c2b[i] - m2[i]) * s + b2[i]; }
    if (i < 256) { float s = g3[i] / sqrtf(v3[i] + 1e-5f); ws[WS_H3 + i] = (c3b[i] - m3[i]) * s + b3[i]; }
}

// ---------------------------------------------------------------------------
// K0b: transformer / feat_proj weights -> f16 (layouts already [N][K])
// ---------------------------------------------------------------------------
__global__ __launch_bounds__(256) void prep_tr_kernel(
    const float* __restrict__ fpw, const float* __restrict__ inw,
    const float* __restrict__ outw, const float* __restrict__ l1w,
    const float* __restrict__ l2w, float* __restrict__ ws)
{
    int i = blockIdx.x * 256 + threadIdx.x;
    _Float16* fpwh = (_Float16*)(ws + WS_FPWH);
    _Float16* inwh = (_Float16*)(ws + WS_INWH);
    _Float16* outwh = (_Float16*)(ws + WS_OUTWH);
    _Float16* l1wh = (_Float16*)(ws + WS_L1WH);
    _Float16* l2wh = (_Float16*)(ws + WS_L2WH);
    if (i < 262144) fpwh[i] = (_Float16)fpw[i];
    if (i < 393216) inwh[i] = (_Float16)inw[i];
    if (i < 131072) outwh[i] = (_Float16)outw[i];
    if (i < 524288) { l1wh[i] = (_Float16)l1w[i]; l2wh[i] = (_Float16)l2w[i]; }
}

// ---------------------------------------------------------------------------
// K1: fused conv1->conv2->conv3->mean-pool via fp16 MFMA.
// Round-8: merged conv2 jj (best ILP: 2 ds_read + 8 MFMA per iter, round-4's
// 449us config) + prefetch, at (256,2) = the proven no-spill point
// ((256,3)+split spilled 44MB, (256,4) spilled 108MB). Keep round-7's
// 2-barriers/tile and x register-pipeline.
// ---------------------------------------------------------------------------
__global__ __launch_bounds__(256, 2) void conv_mfma_kernel(
    const float* __restrict__ x_t, const float* __restrict__ x_f,
    const float* __restrict__ ws, float* __restrict__ pooled)
{
    __shared__ _Float16 xsf[2 * 576];       // [c][l], f16
    __shared__ _Float16 y1[2][132 * 32];    // [parity][row i][ic granule-swizzled]
    __shared__ _Float16 y2s[128 * 64];      // [row n][oc granule-swizzled]
    __shared__ float h1s[32];
    __shared__ float h2s[64];
    __shared__ float h3s[128];
    __shared__ float pbuf[128];

    const int g = blockIdx.x, br = blockIdx.y;
    const int tid = threadIdx.x;
    const int lane = tid & 63, wv = tid >> 6;
    const int l15 = lane & 15, q4 = lane >> 4;

    const float* xin = (br == 0 ? x_t : x_f) + (size_t)g * (Ln * 2);
    const _Float16* w1k = (const _Float16*)(ws + WS_W1K) + br * 1024;
    const _Float16* w2k = (const _Float16*)(ws + WS_W2K) + br * 14336;
    const _Float16* w3k = (const _Float16*)(ws + WS_W3K) + br * 24576;

    if (tid < 32)  h1s[tid] = ws[WS_H1 + br * 32 + tid];
    if (tid < 64)  h2s[tid] = ws[WS_H2 + br * 64 + tid];
    if (tid < 128) { h3s[tid] = ws[WS_H3 + br * 128 + tid]; pbuf[tid] = 0.f; }

    // conv1 A-frags (weights, resident, 8 VGPRs): A[m=l15][k=q4*8+j]
    f16x8 a1[2];
    #pragma unroll
    for (int mt = 0; mt < 2; ++mt)
        a1[mt] = *(const f16x8*)(w1k + (mt * 16 + l15) * 32 + q4 * 8);

    const int mg = wv & 1, ng = wv >> 1;

    const _Float16* w2row = w2k + (size_t)l15 * 224 + q4 * 8;
    const _Float16* w3row = w3k + (size_t)(mg * 64 + l15) * 192 + q4 * 8;

    float pool_[4][4];
    #pragma unroll
    for (int mt = 0; mt < 4; ++mt)
        #pragma unroll
        for (int r = 0; r < 4; ++r) pool_[mt][r] = 0.f;

    const f32x4 vzero = {0.f, 0.f, 0.f, 0.f};

    // ---- prologue: stage tile 0 -> xsf ----
    for (int l = tid; l < 576; l += 256) {
        int xl = -17 + l;
        float a = 0.f, b = 0.f;
        if (xl >= 0 && xl < Ln) { float2 v = *(const float2*)(xin + (size_t)xl * 2); a = v.x; b = v.y; }
        xsf[l] = (_Float16)a; xsf[576 + l] = (_Float16)b;
    }
    __syncthreads();

    #pragma unroll 1
    for (int tile = 0; tile < 9; ++tile) {
        const int P0 = tile * 126;
        const int Q0 = 2 * P0 - 5;

        // ---- conv1 MFMA: M=32 (2 tiles), N=261 (17 tiles), K=32 ----
        const uint* xsu = (const uint*)xsf;
        #pragma unroll 1
        for (int nt = wv; nt < 17; nt += 4) {
            int j0 = nt * 16 + l15;
            union { f16x8 v; uint u[4]; } bf;
            int ubase = (q4 >> 1) * 288 + j0 + (q4 & 1) * 4;
            #pragma unroll
            for (int ii = 0; ii < 4; ++ii) bf.u[ii] = xsu[ubase + ii];
            f32x4 c1acc[2] = {vzero, vzero};
            c1acc[0] = MFMA16(a1[0], bf.v, c1acc[0]);
            c1acc[1] = MFMA16(a1[1], bf.v, c1acc[1]);

            if (j0 <= 260) {
                int q = Q0 + j0;
                bool val = (q >= 0) && (q < 2048);
                int i = j0 >> 1, par = j0 & 1;
                #pragma unroll
                for (int mt = 0; mt < 2; ++mt) {
                    int oc0 = mt * 16 + q4 * 4;
                    union { _Float16 h[4]; uint2 u; } pk;
                    #pragma unroll
                    for (int r = 0; r < 4; ++r) {
                        float y = c1acc[mt][r] + h1s[oc0 + r];
                        y = y > 0.f ? y : 0.f;
                        pk.h[r] = val ? (_Float16)y : (_Float16)0.f;
                    }
                    int gq = mt * 2 + (q4 >> 1), sub = q4 & 1;
                    *(uint2*)(&y1[par][(i * 4 + (gq ^ (i & 3))) * 8 + sub * 4]) = pk.u;
                }
            }
        }
        __syncthreads();   // B2: y1 ready; conv1's xsf reads done

        // ---- issue next tile's x loads (HBM latency overlaps conv2) ----
        float2 xr0 = {0.f, 0.f}, xr1 = {0.f, 0.f}, xr2 = {0.f, 0.f};
        if (tile < 8) {
            const int xn0 = 4 * (P0 + 126) - 17;
            { int xl = xn0 + tid;       if (xl < Ln) xr0 = *(const float2*)(xin + (size_t)xl * 2); }
            { int xl = xn0 + tid + 256; if (xl < Ln) xr1 = *(const float2*)(xin + (size_t)xl * 2); }
            if (tid < 64) { int xl = xn0 + tid + 512; if (xl < Ln) xr2 = *(const float2*)(xin + (size_t)xl * 2); }
        }

        // ---- conv2 MFMA: M=64 (4 tiles), N=128 (wave owns 32), K=224;
        //      merged jj (8 MFMA / 2 ds_read per iter), 1-deep prefetch ----
        {
            f32x4 c2[4][2];
            #pragma unroll
            for (int mt = 0; mt < 4; ++mt) { c2[mt][0] = vzero; c2[mt][1] = vzero; }
            f16x8 a2c[4];
            #pragma unroll
            for (int mt = 0; mt < 4; ++mt)
                a2c[mt] = *(const f16x8*)(w2row + (size_t)mt * 16 * 224);
            #pragma unroll 1
            for (int ks = 0; ks < 7; ++ks) {
                int roff = (ks < 4) ? ks : ks - 4;
                const _Float16* yb = y1[(ks < 4) ? 0 : 1];
                f16x8 bb[2];
                #pragma unroll
                for (int jj = 0; jj < 2; ++jj) {
                    int n = wv * 32 + jj * 16 + l15;
                    int i = n + roff;
                    bb[jj] = *(const f16x8*)(yb + (i * 4 + (q4 ^ (i & 3))) * 8);
                }
                f16x8 a2n[4];
                if (ks < 6) {
                    #pragma unroll
                    for (int mt = 0; mt < 4; ++mt)
                        a2n[mt] = *(const f16x8*)(w2row + (size_t)mt * 16 * 224 + (ks + 1) * 32);
                }
                #pragma unroll
                for (int mt = 0; mt < 4; ++mt) {
                    c2[mt][0] = MFMA16(a2c[mt], bb[0], c2[mt][0]);
                    c2[mt][1] = MFMA16(a2c[mt], bb[1], c2[mt][1]);
                }
                if (ks < 6) {
                    #pragma unroll
                    for (int mt = 0; mt < 4; ++mt) a2c[mt] = a2n[mt];
                }
            }
            #pragma unroll
            for (int jj = 0; jj < 2; ++jj) {
                int n = wv * 32 + jj * 16 + l15;
                int p2 = P0 - 1 + n;
                bool val = (p2 >= 0) && (p2 < 1024);
                #pragma unroll
                for (int mt = 0; mt < 4; ++mt) {
                    int oc0 = mt * 16 + q4 * 4;
                    union { _Float16 h[4]; uint2 u; } pk;
                    #pragma unroll
                    for (int r = 0; r < 4; ++r) {
                        float y = c2[mt][jj][r] + h2s[oc0 + r];
                        y = y > 0.f ? y : 0.f;
                        pk.h[r] = val ? (_Float16)y : (_Float16)0.f;
                    }
                    int gq = oc0 >> 3, sub = q4 & 1;
                    *(uint2*)(&y2s[(n * 8 + (gq ^ (n & 7))) * 8 + sub * 4]) = pk.u;
                }
            }
        }

        // ---- write staged x -> xsf (safe: conv1 reads finished at B2) ----
        if (tile < 8) {
            { int l = tid;       xsf[l] = (_Float16)xr0.x; xsf[576 + l] = (_Float16)xr0.y; }
            { int l = tid + 256; xsf[l] = (_Float16)xr1.x; xsf[576 + l] = (_Float16)xr1.y; }
            if (tid < 64) { int l = tid + 512; xsf[l] = (_Float16)xr2.x; xsf[576 + l] = (_Float16)xr2.y; }
        }
        __syncthreads();   // B3: y2s + staged xsf ready

        // ---- conv3 MFMA + pool: M=128, N=126(128), K=192; two N-halves,
        //      1-deep weight prefetch ----
        #pragma unroll 1
        for (int half = 0; half < 2; ++half) {
            f32x4 c3[4][2];
            #pragma unroll
            for (int mt = 0; mt < 4; ++mt) { c3[mt][0] = vzero; c3[mt][1] = vzero; }
            f16x8 a3c[4];
            #pragma unroll
            for (int mt = 0; mt < 4; ++mt)
                a3c[mt] = *(const f16x8*)(w3row + (size_t)mt * 16 * 192);
            #pragma unroll 1
            for (int ks = 0; ks < 6; ++ks) {
                int t = ks >> 1, ich = ks & 1;
                f16x8 b3[2];
                #pragma unroll
                for (int jj = 0; jj < 2; ++jj) {
                    int np = ng * 64 + (half * 2 + jj) * 16 + l15;
                    int r = np + t; r = r < 128 ? r : 127;   // clamp (masked later)
                    int gq3 = ich * 4 + q4;
                    b3[jj] = *(const f16x8*)(&y2s[(r * 8 + (gq3 ^ (r & 7))) * 8]);
                }
                f16x8 a3n[4];
                if (ks < 5) {
                    #pragma unroll
                    for (int mt = 0; mt < 4; ++mt)
                        a3n[mt] = *(const f16x8*)(w3row + (size_t)mt * 16 * 192 + (ks + 1) * 32);
                }
                #pragma unroll
                for (int mt = 0; mt < 4; ++mt) {
                    c3[mt][0] = MFMA16(a3c[mt], b3[0], c3[mt][0]);
                    c3[mt][1] = MFMA16(a3c[mt], b3[1], c3[mt][1]);
                }
                if (ks < 5) {
                    #pragma unroll
                    for (int mt = 0; mt < 4; ++mt) a3c[mt] = a3n[mt];
                }
            }
            #pragma unroll
            for (int mt = 0; mt < 4; ++mt) {
                int oc0 = mg * 64 + mt * 16 + q4 * 4;
                #pragma unroll
                for (int jj = 0; jj < 2; ++jj) {
                    int np = ng * 64 + (half * 2 + jj) * 16 + l15;
                    int p3 = P0 + np;
                    float valf = ((np < 126) && (p3 < 1024)) ? 1.f : 0.f;
                    #pragma unroll
                    for (int r = 0; r < 4; ++r) {
                        float y = c3[mt][jj][r] + h3s[oc0 + r];
                        y = y > 0.f ? y : 0.f;
                        pool_[mt][r] = fmaf(y, valf, pool_[mt][r]);
                    }
                }
            }
        }
        // no loop-end barrier: conv1(t+1) touches xsf/y1 only; y2s WAR is
        // protected by B2(t+1)
    }

    // ---- pool: reduce over 16 n-lanes, combine waves via LDS, plain store ----
    #pragma unroll
    for (int mt = 0; mt < 4; ++mt)
        #pragma unroll
        for (int r = 0; r < 4; ++r) {
            float v = pool_[mt][r];
            v += __shfl_xor(v, 1, 64);
            v += __shfl_xor(v, 2, 64);
            v += __shfl_xor(v, 4, 64);
            v += __shfl_xor(v, 8, 64);
            if (l15 == 0) atomicAdd(&pbuf[mg * 64 + mt * 16 + q4 * 4 + r], v);
        }
    __syncthreads();
    if (tid < 128) pooled[g * 256 + br * 128 + tid] = pbuf[tid] * (1.f / 1024.f);
}

// ---------------------------------------------------------------------------
// K2: GAT -> f16 gat_out [g][1024]. One block per g.
// ---------------------------------------------------------------------------
__global__ __launch_bounds__(256) void gat_kernel(
    const float* __restrict__ glw, const float* __restrict__ att_src,
    const float* __restrict__ att_dst, const float* __restrict__ gbias,
    const float* __restrict__ pooled, _Float16* __restrict__ gouth)
{
    __shared__ float feats[256];
    __shared__ float hs[4 * 256];
    __shared__ float av[32];
    __shared__ float alpha[64];

    int g = blockIdx.x, tid = threadIdx.x;
    feats[tid] = pooled[g * 256 + tid];
    __syncthreads();

    { // h[n,o] = sum_c feat[n,c] * W[o,c]
        int o = tid;
        const float* w = glw + o * 64;
        float a0 = 0, a1 = 0, a2 = 0, a3 = 0;
        for (int c = 0; c < 64; ++c) {
            float wvv = w[c];
            a0 = fmaf(feats[c],       wvv, a0);
            a1 = fmaf(feats[64 + c],  wvv, a1);
            a2 = fmaf(feats[128 + c], wvv, a2);
            a3 = fmaf(feats[192 + c], wvv, a3);
        }
        hs[o] = a0; hs[256 + o] = a1; hs[512 + o] = a2; hs[768 + o] = a3;
    }
    __syncthreads();

    if (tid < 32) {
        int n = (tid & 15) >> 2, hd = tid & 3;
        const float* aw = (tid < 16) ? att_src : att_dst;
        float s = 0;
        for (int d = 0; d < 64; ++d) s = fmaf(hs[n * 256 + hd * 64 + d], aw[hd * 64 + d], s);
        av[tid] = s;
    }
    __syncthreads();

    if (tid < 16) {
        int i = tid >> 2, hd = tid & 3;
        float sc[4], mx = -1e30f;
        #pragma unroll
        for (int j = 0; j < 4; ++j) {
            float v = av[16 + i * 4 + hd] + av[j * 4 + hd];
            v = v > 0.f ? v : 0.2f * v;
            sc[j] = v; mx = fmaxf(mx, v);
        }
        float den = 0;
        #pragma unroll
        for (int j = 0; j < 4; ++j) { sc[j] = expf(sc[j] - mx); den += sc[j]; }
        #pragma unroll
        for (int j = 0; j < 4; ++j) alpha[(i * 4 + j) * 4 + hd] = sc[j] / den;
    }
    __syncthreads();

    { // gat_out[i,o] -> f16 global
        int o = tid, hd = o >> 6;
        #pragma unroll
        for (int i = 0; i < 4; ++i) {
            float acc = gbias[o];
            #pragma unroll
            for (int j = 0; j < 4; ++j) acc = fmaf(alpha[(i * 4 + j) * 4 + hd], hs[j * 256 + o], acc);
            gouth[(size_t)g * 1024 + i * 256 + o] = (_Float16)acc;
        }
    }
}

// ---------------------------------------------------------------------------
// feat_proj GEMM + PE: C[m][n] = A[m][K].W[n][K] + bias + pe -> f32 + f16.
// Block tile 64x64, wave 16x64.
// ---------------------------------------------------------------------------
__global__ __launch_bounds__(256) void fproj_gemm_kernel(
    const _Float16* __restrict__ A, const _Float16* __restrict__ W,
    const float* __restrict__ bias, float* __restrict__ out32,
    _Float16* __restrict__ out16)
{
    const int tid = threadIdx.x;
    const int wv = tid >> 6, l15 = tid & 15, q4 = (tid & 63) >> 4;
    const int m0 = blockIdx.x * 64 + wv * 16;
    const int n0 = blockIdx.y * 64;
    constexpr int K = 1024;

    const f32x4 vzero = {0.f, 0.f, 0.f, 0.f};
    f32x4 acc[4] = {vzero, vzero, vzero, vzero};

    const _Float16* arow = A + (size_t)(m0 + l15) * K + q4 * 8;
    #pragma unroll 4
    for (int ks = 0; ks < K / 32; ++ks) {
        f16x8 a = *(const f16x8*)(arow + ks * 32);
        #pragma unroll
        for (int nt = 0; nt < 4; ++nt) {
            f16x8 b = *(const f16x8*)(W + (size_t)(n0 + nt * 16 + l15) * K + ks * 32 + q4 * 8);
            acc[nt] = MFMA16(a, b, acc[nt]);
        }
    }

    #pragma unroll
    for (int nt = 0; nt < 4; ++nt) {
        int n = n0 + nt * 16 + l15;
        float bs = bias[n];
        int kk = n >> 1;
        float dv = expf((float)kk * -0.07195588f);  // -2*ln(1e4)/256
        #pragma unroll
        for (int r = 0; r < 4; ++r) {
            int m = m0 + q4 * 4 + r;
            float v = acc[nt][r] + bs;
            float arg = (float)(m % 3) * dv;
            v += (n & 1) ? cosf(arg) : sinf(arg);
            out32[(size_t)m * 256 + n] = v;
            out16[(size_t)m * 256 + n] = (_Float16)v;
        }
    }
}

// ---------------------------------------------------------------------------
// Fused attention block: per-batch b (256 blocks):
//   QKV = XH[3] @ inw^T + inb  (MFMA, M=16 padded, rows>=3 masked)
//   attn (wave per head, S=3, shuffle softmax)
//   out-proj + bias + residual + LN1 -> X, XH
// ---------------------------------------------------------------------------
__global__ __launch_bounds__(256) void attn_fused_kernel(
    _Float16* __restrict__ XH, float* __restrict__ X,
    const _Float16* __restrict__ inw, const float* __restrict__ inb,
    const _Float16* __restrict__ outw, const float* __restrict__ outb,
    const float* __restrict__ gamma, const float* __restrict__ beta)
{
    __shared__ _Float16 xls[3 * 264];
    __shared__ float qkvl[3 * 768];
    __shared__ _Float16 aout[3 * 264];
    __shared__ float ys[3][256];

    const int b = blockIdx.x, tid = threadIdx.x;
    const int wv = tid >> 6, lane = tid & 63;
    const int l15 = tid & 15, q4 = (tid & 63) >> 4;
    const int ml = (l15 < 3) ? l15 : 2;   // clamped A-row (rows 3..15 unused)

    for (int idx = tid; idx < 768; idx += 256)
        xls[(idx >> 8) * 264 + (idx & 255)] = XH[(size_t)b * 768 + idx];
    __syncthreads();

    // ---- QKV GEMM: N=768 (12 tiles/wave), K=256 ----
    {
        const int n0w = wv * 192;
        const _Float16* arow = xls + ml * 264 + q4 * 8;
        #pragma unroll 1
        for (int nt = 0; nt < 12; ++nt) {
            int col = n0w + nt * 16 + l15;
            f32x4 acc = {0.f, 0.f, 0.f, 0.f};
            #pragma unroll
            for (int ks = 0; ks < 8; ++ks) {
                f16x8 a = *(const f16x8*)(arow + ks * 32);
                f16x8 bf = *(const f16x8*)(inw + (size_t)col * 256 + ks * 32 + q4 * 8);
                acc = MFMA16(a, bf, acc);
            }
            if (q4 == 0) {
                float bsv = inb[col];
                #pragma unroll
                for (int r = 0; r < 3; ++r)
                    qkvl[r * 768 + col] = acc[r] + bsv;
            }
        }
    }
    __syncthreads();

    // ---- attention: wave wv = head, lane = dim ----
    {
        const int hb = wv * 64 + lane;
        float q[3], k[3], v[3];
        #pragma unroll
        for (int s = 0; s < 3; ++s) {
            q[s] = qkvl[s * 768 + hb];
            k[s] = qkvl[s * 768 + 256 + hb];
            v[s] = qkvl[s * 768 + 512 + hb];
        }
        float sc[3][3];
        #pragma unroll
        for (int si = 0; si < 3; ++si)
            #pragma unroll
            for (int sj = 0; sj < 3; ++sj) {
                float p = q[si] * k[sj];
                #pragma unroll
                for (int m = 32; m > 0; m >>= 1) p += __shfl_xor(p, m, 64);
                sc[si][sj] = p * 0.125f;   // 1/sqrt(64)
            }
        #pragma unroll
        for (int si = 0; si < 3; ++si) {
            float mx = fmaxf(sc[si][0], fmaxf(sc[si][1], sc[si][2]));
            float e0 = expf(sc[si][0] - mx), e1 = expf(sc[si][1] - mx), e2 = expf(sc[si][2] - mx);
            float den = e0 + e1 + e2;
            float o = (e0 * v[0] + e1 * v[1] + e2 * v[2]) / den;
            aout[si * 264 + hb] = (_Float16)o;
        }
    }
    __syncthreads();

    // ---- out-proj: N=256 (4 tiles/wave), K=256 + bias + residual ----
    {
        const int n0w = wv * 64;
        const _Float16* arow = aout + ml * 264 + q4 * 8;
        #pragma unroll 1
        for (int nt = 0; nt < 4; ++nt) {
            int col = n0w + nt * 16 + l15;
            f32x4 acc = {0.f, 0.f, 0.f, 0.f};
            #pragma unroll
            for (int ks = 0; ks < 8; ++ks) {
                f16x8 a = *(const f16x8*)(arow + ks * 32);
                f16x8 bf = *(const f16x8*)(outw + (size_t)col * 256 + ks * 32 + q4 * 8);
                acc = MFMA16(a, bf, acc);
            }
            if (q4 == 0) {
                float bsv = outb[col];
                #pragma unroll
                for (int r = 0; r < 3; ++r)
                    ys[r][col] = acc[r] + bsv + X[((size_t)b * 3 + r) * 256 + col];
            }
        }
    }
    __syncthreads();

    // ---- LN per row (waves 0-2) ----
    if (wv < 3) {
        float s = 0.f, s2 = 0.f;
        #pragma unroll
        for (int c0 = 0; c0 < 256; c0 += 64) {
            float v = ys[wv][c0 + lane]; s += v; s2 += v * v;
        }
        #pragma unroll
        for (int m = 32; m > 0; m >>= 1) { s += __shfl_xor(s, m, 64); s2 += __shfl_xor(s2, m, 64); }
        float mu = s * (1.f / 256.f);
        float var = s2 * (1.f / 256.f) - mu * mu;
        float inv = 1.f / sqrtf(var + 1e-5f);
        #pragma unroll
        for (int c0 = 0; c0 < 256; c0 += 64) {
            int c = c0 + lane;
            float v = (ys[wv][c] - mu) * inv * gamma[c] + beta[c];
            X[((size_t)b * 3 + wv) * 256 + c] = v;
            XH[((size_t)b * 3 + wv) * 256 + c] = (_Float16)v;
        }
    }
}

// ---------------------------------------------------------------------------
// Fused FFN block: 16 rows/block (48 blocks):
//   mid = relu(XH @ l1w^T + l1b)   (LDS-resident, never to HBM)
//   y   = mid @ l2w^T + l2b + X ; LN2 -> X, XH
// ---------------------------------------------------------------------------
__global__ __launch_bounds__(256) void ffn_fused_kernel(
    _Float16* __restrict__ XH, float* __restrict__ X,
    const _Float16* __restrict__ l1w, const float* __restrict__ l1b,
    const _Float16* __restrict__ l2w, const float* __restrict__ l2b,
    const float* __restrict__ gamma, const float* __restrict__ beta)
{
    __shared__ _Float16 xls[16 * 264];
    __shared__ _Float16 mid[16 * 1032];
    __shared__ float ys[16][260];

    const int tid = threadIdx.x;
    const int wv = tid >> 6, l15 = tid & 15, q4 = (tid & 63) >> 4;
    const int r0 = blockIdx.x * 16;

    for (int idx = tid; idx < 4096; idx += 256)
        xls[(idx >> 8) * 264 + (idx & 255)] = XH[(size_t)r0 * 256 + idx];
    __syncthreads();

    // ---- ffn1: N=1024 (16 tiles/wave), K=256; relu -> mid (LDS) ----
    {
        const _Float16* arow = xls + l15 * 264 + q4 * 8;
        #pragma unroll 1
        for (int nt = 0; nt < 16; ++nt) {
            int col = wv * 256 + nt * 16 + l15;
            f32x4 acc = {0.f, 0.f, 0.f, 0.f};
            #pragma unroll
            for (int ks = 0; ks < 8; ++ks) {
                f16x8 a = *(const f16x8*)(arow + ks * 32);
                f16x8 bf = *(const f16x8*)(l1w + (size_t)col * 256 + ks * 32 + q4 * 8);
                acc = MFMA16(a, bf, acc);
            }
            float bsv = l1b[col];
            #pragma unroll
            for (int r = 0; r < 4; ++r) {
                float v = fmaxf(acc[r] + bsv, 0.f);
                mid[(q4 * 4 + r) * 1032 + col] = (_Float16)v;
            }
        }
    }
    __syncthreads();

    // ---- ffn2: N=256 (4 tiles/wave), K=1024 from mid ----
    {
        const _Float16* arow = mid + l15 * 1032 + q4 * 8;
        const f32x4 vzero = {0.f, 0.f, 0.f, 0.f};
        f32x4 acc[4] = {vzero, vzero, vzero, vzero};
        #pragma unroll 2
        for (int ks = 0; ks < 32; ++ks) {
            f16x8 a = *(const f16x8*)(arow + ks * 32);
            #pragma unroll
            for (int nt = 0; nt < 4; ++nt) {
                f16x8 bf = *(const f16x8*)(l2w + (size_t)(wv * 64 + nt * 16 + l15) * 1024 + ks * 32 + q4 * 8);
                acc[nt] = MFMA16(a, bf, acc[nt]);
            }
        }
        #pragma unroll
        for (int nt = 0; nt < 4; ++nt) {
            int col = wv * 64 + nt * 16 + l15;
            float bsv = l2b[col];
            #pragma unroll
            for (int r = 0; r < 4; ++r) {
                int row = q4 * 4 + r;
                ys[row][col] = acc[nt][r] + bsv + X[(size_t)(r0 + row) * 256 + col];
            }
        }
    }
    __syncthreads();

    // ---- LN: 16 rows x 16 lanes ----
    {
        int row = tid >> 4, l16 = tid & 15;
        float s = 0.f, s2 = 0.f;
        #pragma unroll
        for (int c0 = 0; c0 < 256; c0 += 16) {
            float v = ys[row][c0 + l16]; s += v; s2 += v * v;
        }
        s += __shfl_xor(s, 1, 64);  s2 += __shfl_xor(s2, 1, 64);
        s += __shfl_xor(s, 2, 64);  s2 += __shfl_xor(s2, 2, 64);
        s += __shfl_xor(s, 4, 64);  s2 += __shfl_xor(s2, 4, 64);
        s += __shfl_xor(s, 8, 64);  s2 += __shfl_xor(s2, 8, 64);
        float mu = s * (1.f / 256.f);
        float var = s2 * (1.f / 256.f) - mu * mu;
        float inv = 1.0f / sqrtf(var + 1e-5f);
        #pragma unroll
        for (int c0 = 0; c0 < 256; c0 += 16) {
            int c = c0 + l16;
            float v = (ys[row][c] - mu) * inv * gamma[c] + beta[c];
            X[(size_t)(r0 + row) * 256 + c] = v;
            XH[(size_t)(r0 + row) * 256 + c] = (_Float16)v;
        }
    }
}

// ---------------------------------------------------------------------------
// Head: temporal attention + fc1/relu + fc2/relu + fc3. One block per b.
// ---------------------------------------------------------------------------
__global__ __launch_bounds__(256) void head_kernel(
    const float* __restrict__ X, const float* __restrict__ taw, const float* __restrict__ tab,
    const float* __restrict__ f1w, const float* __restrict__ f1b,
    const float* __restrict__ f2w, const float* __restrict__ f2b,
    const float* __restrict__ f3w, const float* __restrict__ f3b,
    float* __restrict__ out)
{
    __shared__ float xs[3 * 256];
    __shared__ float wsm[3];
    __shared__ float cs[256];
    __shared__ float a1[128];
    __shared__ float a2[64];
    int b = blockIdx.x, tid = threadIdx.x;
    for (int idx = tid; idx < 768; idx += 256) xs[idx] = X[(size_t)b * 768 + idx];
    __syncthreads();
    if (tid < 3) {
        float s = tab[0];
        for (int d = 0; d < 256; ++d) s = fmaf(xs[tid * 256 + d], taw[d], s);
        wsm[tid] = s;
    }
    __syncthreads();
    {
        float m = fmaxf(wsm[0], fmaxf(wsm[1], wsm[2]));
        float e0 = expf(wsm[0] - m), e1 = expf(wsm[1] - m), e2 = expf(wsm[2] - m);
        float den = e0 + e1 + e2;
        cs[tid] = (e0 * xs[tid] + e1 * xs[256 + tid] + e2 * xs[512 + tid]) / den;
    }
    __syncthreads();
    if (tid < 128) {
        float a = f1b[tid];
        const float* w = f1w + tid * 256;
        for (int c = 0; c < 256; ++c) a = fmaf(cs[c], w[c], a);
        a1[tid] = fmaxf(a, 0.f);
    }
    __syncthreads();
    if (tid < 64) {
        float a = f2b[tid];
        const float* w = f2w + tid * 128;
        for (int c = 0; c < 128; ++c) a = fmaf(a1[c], w[c], a);
        a2[tid] = fmaxf(a, 0.f);
    }
    __syncthreads();
    if (tid < 5) {
        float a = f3b[tid];
        const float* w = f3w + tid * 64;
        for (int c = 0; c < 64; ++c) a = fmaf(a2[c], w[c], a);
        out[b * 5 + tid] = a;
    }
}

// ---------------------------------------------------------------------------
extern "C" void kernel_launch(void* const* d_in, const int* in_sizes, int n_in,
                              void* d_out, int out_size, void* d_ws, size_t ws_size,
                              hipStream_t stream) {
    const float* x_t     = (const float*)d_in[0];
    const float* x_f     = (const float*)d_in[1];
    const float* conv1_w = (const float*)d_in[2];
    const float* conv1_b = (const float*)d_in[3];
    const float* bn1_g   = (const float*)d_in[4];
    const float* bn1_b   = (const float*)d_in[5];
    const float* bn1_m   = (const float*)d_in[6];
    const float* bn1_v   = (const float*)d_in[7];
    const float* conv2_w = (const float*)d_in[8];
    const float* conv2_b = (const float*)d_in[9];
    const float* bn2_g   = (const float*)d_in[10];
    const float* bn2_b   = (const float*)d_in[11];
    const float* bn2_m   = (const float*)d_in[12];
    const float* bn2_v   = (const float*)d_in[13];
    const float* conv3_w = (const float*)d_in[14];
    const float* conv3_b = (const float*)d_in[15];
    const float* bn3_g   = (const float*)d_in[16];
    const float* bn3_b   = (const float*)d_in[17];
    const float* bn3_m   = (const float*)d_in[18];
    const float* bn3_v   = (const float*)d_in[19];
    const float* gat_lin_w   = (const float*)d_in[20];
    const float* gat_att_src = (const float*)d_in[21];
    const float* gat_att_dst = (const float*)d_in[22];
    const float* gat_bias    = (const float*)d_in[23];
    const float* feat_proj_w = (const float*)d_in[24];
    const float* feat_proj_b = (const float*)d_in[25];
    const float* tr_in_w  = (const float*)d_in[26];
    const float* tr_in_b  = (const float*)d_in[27];
    const float* tr_out_w = (const float*)d_in[28];
    const float* tr_out_b = (const float*)d_in[29];
    const float* tr_l1_w  = (const float*)d_in[30];
    const float* tr_l1_b  = (const float*)d_in[31];
    const float* tr_l2_w  = (const float*)d_in[32];
    const float* tr_l2_b  = (const float*)d_in[33];
    const float* tr_ln1_g = (const float*)d_in[34];
    const float* tr_ln1_b = (const float*)d_in[35];
    const float* tr_ln2_g = (const float*)d_in[36];
    const float* tr_ln2_b = (const float*)d_in[37];
    const float* ta_w  = (const float*)d_in[38];
    const float* ta_b  = (const float*)d_in[39];
    const float* fc1_w = (const float*)d_in[40];
    const float* fc1_b = (const float*)d_in[41];
    const float* fc2_w = (const float*)d_in[42];
    const float* fc2_b = (const float*)d_in[43];
    const float* fc3_w = (const float*)d_in[44];
    const float* fc3_b = (const float*)d_in[45];

    float* ws    = (float*)d_ws;
    float* POOL  = ws + WS_POOL;
    float* X     = ws + WS_X;
    _Float16* GOUTH = (_Float16*)(ws + WS_SCR);
    _Float16* XH    = (_Float16*)(ws + WS_XH);
    const _Float16* FPWH  = (const _Float16*)(ws + WS_FPWH);
    const _Float16* INWH  = (const _Float16*)(ws + WS_INWH);
    const _Float16* OUTWH = (const _Float16*)(ws + WS_OUTWH);
    const _Float16* L1WH  = (const _Float16*)(ws + WS_L1WH);
    const _Float16* L2WH  = (const _Float16*)(ws + WS_L2WH);
    float* out = (float*)d_out;

    prep_kernel<<<192, 256, 0, stream>>>(conv1_w, conv2_w, conv3_w,
        conv1_b, bn1_g, bn1_b, bn1_m, bn1_v,
        conv2_b, bn2_g, bn2_b, bn2_m, bn2_v,
        conv3_b, bn3_g, bn3_b, bn3_m, bn3_v, ws);
    prep_tr_kernel<<<2048, 256, 0, stream>>>(feat_proj_w, tr_in_w, tr_out_w,
                                             tr_l1_w, tr_l2_w, ws);

    conv_mfma_kernel<<<dim3(Gn, 2), 256, 0, stream>>>(x_t, x_f, ws, POOL);

    gat_kernel<<<Gn, 256, 0, stream>>>(gat_lin_w, gat_att_src, gat_att_dst, gat_bias,
                                       POOL, GOUTH);

    // feat_proj + PE: X/XH = GOUTH @ fpw^T + fpb + pe  (M=768, K=1024, N=256)
    fproj_gemm_kernel<<<dim3(12, 4), 256, 0, stream>>>(
        GOUTH, FPWH, feat_proj_b, X, XH);

    for (int l = 0; l < TLn; ++l) {
        attn_fused_kernel<<<Bn, 256, 0, stream>>>(
            XH, X, INWH + (size_t)l * 196608, tr_in_b + l * 768,
            OUTWH + (size_t)l * 65536, tr_out_b + l * 256,
            tr_ln1_g + l * 256, tr_ln1_b + l * 256);
        ffn_fused_kernel<<<Gn / 16, 256, 0, stream>>>(
            XH, X, L1WH + (size_t)l * 262144, tr_l1_b + l * 1024,
            L2WH + (size_t)l * 262144, tr_l2_b + l * 256,
            tr_ln2_g + l * 256, tr_ln2_b + l * 256);
    }

    head_kernel<<<Bn, 256, 0, stream>>>(X, ta_w, ta_b, fc1_w, fc1_b,
                                        fc2_w, fc2_b, fc3_w, fc3_b, out);
}